// Round 14
// baseline (816.844 us; speedup 1.0000x reference)
//
#include <hip/hip_runtime.h>

#define NMAP 128
#define EPSV 1e-5f
#define SCHUNK 2048     // elements per scan block (256 thr x 8)
#define HSTR 136        // LDS h-tile row stride in shorts (272 B)
#define BKSH 8          // 256 nodes per bucket
#define CH 8192         // edges per bucket_scatter workgroup

typedef __attribute__((ext_vector_type(8))) short bf16x8;   // 8 bf16 = 4 VGPRs
typedef __attribute__((ext_vector_type(4))) float f32x4;

__device__ __forceinline__ unsigned short f2bf(float f) {
    union { float f; unsigned u; } x; x.f = f;
    unsigned u = x.u;
    return (unsigned short)((u + 0x7fffu + ((u >> 16) & 1u)) >> 16);  // RNE
}
__device__ __forceinline__ float bf2f(unsigned short h) {
    union { unsigned u; float f; } x; x.u = ((unsigned)h) << 16;
    return x.f;
}
// two f32 -> packed bf16 pair (RNE, same rounding as f2bf), 1 VALU op
__device__ __forceinline__ unsigned cvt_pk_bf16(float lo, float hi) {
    unsigned r;
    asm("v_cvt_pk_bf16_f32 %0, %1, %2" : "=v"(r) : "v"(lo), "v"(hi));
    return r;
}

// M=32 tile: 4 waves; wave w -> cols [w*32,(w+1)*32), 2x2 fragments.
// row = mi*16 + lhi*4 + j (mi<2), col = w*32 + ni*16 + l15 (ni<2).
struct __align__(16) FSmem {
    unsigned short h[32 * HSTR];    // 8704 B  bf16 h-tile [32][136]
    unsigned short res[32 * HSTR];  // 8704 B  residual / h1o staging tile
    float2 red[4][4][34];           // 4352 B  GN partials [w][cg][row], (sum,ss)
    float mv[32][2];                //  256 B  mean/rstd per row
};

// per-row mean/rstd over 128 cols -> s.mv  (2 shfl stages + packed LDS finish)
__device__ __forceinline__ void gn_stats(FSmem& s, const f32x4 acc[2][2],
                                         int w, int l15, int lhi, int tid)
{
    const int cg = l15 >> 2;
    #pragma unroll
    for (int mi = 0; mi < 2; ++mi) {
        #pragma unroll
        for (int j = 0; j < 4; ++j) {
            float a0 = acc[mi][0][j], a1 = acc[mi][1][j];
            float s0 = a0 + a1, s1 = a0 * a0 + a1 * a1;
            s0 += __shfl_xor(s0, 1); s1 += __shfl_xor(s1, 1);
            s0 += __shfl_xor(s0, 2); s1 += __shfl_xor(s1, 2);
            if ((l15 & 3) == 0) {
                int row = mi * 16 + lhi * 4 + j;
                s.red[w][cg][row] = make_float2(s0, s1);
            }
        }
    }
    __syncthreads();
    if (tid < 32) {
        float sm = 0.f, ss = 0.f;
        #pragma unroll
        for (int ww = 0; ww < 4; ++ww)
            #pragma unroll
            for (int cgg = 0; cgg < 4; ++cgg) {
                float2 p = s.red[ww][cgg][tid];
                sm += p.x; ss += p.y;
            }
        float mean = sm * (1.f / 128.f);
        float var = ss * (1.f / 128.f) - mean * mean;
        s.mv[tid][0] = mean;
        s.mv[tid][1] = rsqrtf(var + EPSV);
    }
    __syncthreads();
}

// acc += h_lds @ WT[kwoff..]   (A from s.h, B loaded inline)
__device__ __forceinline__ void gemm_lds(f32x4 acc[2][2], const FSmem& s,
    const unsigned short* __restrict__ WT, int K, int kwoff, int nks,
    int w, int l15, int lhi)
{
    #pragma unroll
    for (int ks = 0; ks < nks; ++ks) {
        bf16x8 af[2], bfr[2];
        #pragma unroll
        for (int mi = 0; mi < 2; ++mi)
            af[mi] = *(const bf16x8*)&s.h[(mi * 16 + l15) * HSTR + ks * 32 + lhi * 8];
        #pragma unroll
        for (int ni = 0; ni < 2; ++ni)
            bfr[ni] = *(const bf16x8*)&WT[(size_t)(w * 32 + ni * 16 + l15) * K + kwoff + ks * 32 + lhi * 8];
        #pragma unroll
        for (int mi = 0; mi < 2; ++mi)
            #pragma unroll
            for (int ni = 0; ni < 2; ++ni)
                acc[mi][ni] = __builtin_amdgcn_mfma_f32_16x16x32_bf16(
                    af[mi], bfr[ni], acc[mi][ni], 0, 0, 0);
    }
}

// acc += [Xf|Xa] @ WT (K=256), halves interleaved; wave 0 stashes Xf tile -> s.res
__device__ __forceinline__ void gemm_fc2(f32x4 acc[2][2], FSmem& s,
    const unsigned short* __restrict__ Xf, const unsigned short* __restrict__ Xa,
    const unsigned short* __restrict__ WT,
    int rowbase, int w, int l15, int lhi)
{
    #pragma unroll
    for (int ks = 0; ks < 4; ++ks) {
        bf16x8 afF[2], afA[2], bF[2], bA[2];
        #pragma unroll
        for (int mi = 0; mi < 2; ++mi) {
            size_t ro = (size_t)(rowbase + mi * 16 + l15) * 128 + ks * 32 + lhi * 8;
            afF[mi] = *(const bf16x8*)&Xf[ro];
            afA[mi] = *(const bf16x8*)&Xa[ro];
        }
        if (w == 0) {
            #pragma unroll
            for (int mi = 0; mi < 2; ++mi)
                *(bf16x8*)&s.res[(mi * 16 + l15) * HSTR + ks * 32 + lhi * 8] = afF[mi];
        }
        #pragma unroll
        for (int ni = 0; ni < 2; ++ni) {
            size_t co = (size_t)(w * 32 + ni * 16 + l15) * 256 + ks * 32 + lhi * 8;
            bF[ni] = *(const bf16x8*)&WT[co];
            bA[ni] = *(const bf16x8*)&WT[co + 128];
        }
        #pragma unroll
        for (int mi = 0; mi < 2; ++mi)
            #pragma unroll
            for (int ni = 0; ni < 2; ++ni) {
                acc[mi][ni] = __builtin_amdgcn_mfma_f32_16x16x32_bf16(
                    afF[mi], bF[ni], acc[mi][ni], 0, 0, 0);
                acc[mi][ni] = __builtin_amdgcn_mfma_f32_16x16x32_bf16(
                    afA[mi], bA[ni], acc[mi][ni], 0, 0, 0);
            }
    }
}

// GN + relu -> s.h  (cvt_pk pairs the two ni columns)
__device__ __forceinline__ void epi_lds(const f32x4 acc[2][2], FSmem& s,
    const float* __restrict__ g, const float* __restrict__ b, int w, int l15, int lhi)
{
    float gv[2], bv[2];
    #pragma unroll
    for (int ni = 0; ni < 2; ++ni) {
        int col = w * 32 + ni * 16 + l15;
        gv[ni] = g[col]; bv[ni] = b[col];
    }
    #pragma unroll
    for (int mi = 0; mi < 2; ++mi)
        #pragma unroll
        for (int j = 0; j < 4; ++j) {
            int row = mi * 16 + lhi * 4 + j;
            float mean = s.mv[row][0], rstd = s.mv[row][1];
            float v0 = fmaxf((acc[mi][0][j] - mean) * rstd * gv[0] + bv[0], 0.f);
            float v1 = fmaxf((acc[mi][1][j] - mean) * rstd * gv[1] + bv[1], 0.f);
            unsigned pk = cvt_pk_bf16(v0, v1);
            int c0 = w * 32 + l15;
            s.h[row * HSTR + c0]      = (unsigned short)pk;
            s.h[row * HSTR + c0 + 16] = (unsigned short)(pk >> 16);
        }
}

// GN in-register (no relu)
__device__ __forceinline__ void norm_reg(f32x4 acc[2][2], const FSmem& s,
    const float* __restrict__ g, const float* __restrict__ b, int w, int l15, int lhi)
{
    float gv[2], bv[2];
    #pragma unroll
    for (int ni = 0; ni < 2; ++ni) {
        int col = w * 32 + ni * 16 + l15;
        gv[ni] = g[col]; bv[ni] = b[col];
    }
    #pragma unroll
    for (int mi = 0; mi < 2; ++mi)
        #pragma unroll
        for (int j = 0; j < 4; ++j) {
            int row = mi * 16 + lhi * 4 + j;
            float mean = s.mv[row][0], rstd = s.mv[row][1];
            #pragma unroll
            for (int ni = 0; ni < 2; ++ni)
                acc[mi][ni][j] = (acc[mi][ni][j] - mean) * rstd * gv[ni] + bv[ni];
        }
}

// vectorized tile writeout: LDS [32][HSTR] -> global row-major [rowbase..][128]
__device__ __forceinline__ void vec_out(const unsigned short* __restrict__ t,
    unsigned short* __restrict__ dst, int rowbase, int nrows, int tid)
{
    #pragma unroll
    for (int it = 0; it < 2; ++it) {
        int c = tid * 2 + it;              // 0..511
        int row = c >> 4, col8 = (c & 15) * 8;
        if (rowbase + row < nrows)
            *(bf16x8*)&dst[(size_t)(rowbase + row) * NMAP + col8] =
                *(const bf16x8*)&t[row * HSTR + col8];
    }
}

// vectorized tile writeout into chunk-major h1: [8][N][16ch]
__device__ __forceinline__ void vec_out_chunk(const unsigned short* __restrict__ t,
    unsigned short* __restrict__ dst, int rowbase, int nrows, int tid, int N)
{
    #pragma unroll
    for (int it = 0; it < 2; ++it) {
        int c = tid * 2 + it;              // 0..511
        int row = c >> 4, col8 = (c & 15) * 8;
        int chunk = col8 >> 4;             // 0..7
        int cc = col8 & 15;                // 0 or 8
        if (rowbase + row < nrows)
            *(bf16x8*)&dst[((size_t)chunk * N + rowbase + row) * 16 + cc] =
                *(const bf16x8*)&t[row * HSTR + col8];
    }
}

// ---------------------------------------------------------------------------
// input stage + first fc1, all fused (M=32 tile)
__global__ __launch_bounds__(256) void input_fused(
    const unsigned short* __restrict__ X32,       // [N+64][32] bf16
    const unsigned short* __restrict__ wts,
    const float* __restrict__ g1, const float* __restrict__ b1,
    const float* __restrict__ gt, const float* __restrict__ bt,
    const float* __restrict__ g2, const float* __restrict__ b2,
    const float* __restrict__ g1n, const float* __restrict__ b1n,
    unsigned short* __restrict__ fbf, unsigned short* __restrict__ h1bf,
    int nrows)
{
    __shared__ FSmem s;
    const int tid = threadIdx.x;
    const int w = tid >> 6, l = tid & 63, l15 = l & 15, lhi = l >> 4;
    const int rowbase = blockIdx.x * 32;

    const unsigned short* w1T = wts;              // K=32
    const unsigned short* wtT = wts + 4096;       // K=32
    const unsigned short* w2T = wts + 8192;       // K=128
    const unsigned short* f1T = wts + 24576;      // fc1[0], K=128

    f32x4 accA[2][2] = {}, accT[2][2] = {};
    {
        bf16x8 af[2], b1f[2], btf[2];
        #pragma unroll
        for (int mi = 0; mi < 2; ++mi)
            af[mi] = *(const bf16x8*)&X32[(size_t)(rowbase + mi * 16 + l15) * 32 + lhi * 8];
        #pragma unroll
        for (int ni = 0; ni < 2; ++ni) {
            int col = w * 32 + ni * 16 + l15;
            b1f[ni] = *(const bf16x8*)&w1T[(size_t)col * 32 + lhi * 8];
            btf[ni] = *(const bf16x8*)&wtT[(size_t)col * 32 + lhi * 8];
        }
        #pragma unroll
        for (int mi = 0; mi < 2; ++mi)
            #pragma unroll
            for (int ni = 0; ni < 2; ++ni) {
                accA[mi][ni] = __builtin_amdgcn_mfma_f32_16x16x32_bf16(af[mi], b1f[ni], accA[mi][ni], 0, 0, 0);
                accT[mi][ni] = __builtin_amdgcn_mfma_f32_16x16x32_bf16(af[mi], btf[ni], accT[mi][ni], 0, 0, 0);
            }
    }

    gn_stats(s, accT, w, l15, lhi, tid);
    norm_reg(accT, s, gt, bt, w, l15, lhi);       // T = GN(X@wt), no relu
    gn_stats(s, accA, w, l15, lhi, tid);
    epi_lds(accA, s, g1, b1, w, l15, lhi);        // h1 -> s.h
    __syncthreads();

    // stage 1: feat = relu(GN(h1@w2) + T) -> s.h only
    f32x4 accB[2][2] = {};
    gemm_lds(accB, s, w2T, 128, 0, 4, w, l15, lhi);
    gn_stats(s, accB, w, l15, lhi, tid);
    {
        float gv[2], bv[2];
        #pragma unroll
        for (int ni = 0; ni < 2; ++ni) {
            int col = w * 32 + ni * 16 + l15;
            gv[ni] = g2[col]; bv[ni] = b2[col];
        }
        #pragma unroll
        for (int mi = 0; mi < 2; ++mi)
            #pragma unroll
            for (int j = 0; j < 4; ++j) {
                int rl = mi * 16 + lhi * 4 + j;
                float mean = s.mv[rl][0], rstd = s.mv[rl][1];
                float v0 = fmaxf((accB[mi][0][j] - mean) * rstd * gv[0] + bv[0]
                                 + accT[mi][0][j], 0.f);
                float v1 = fmaxf((accB[mi][1][j] - mean) * rstd * gv[1] + bv[1]
                                 + accT[mi][1][j], 0.f);
                unsigned pk = cvt_pk_bf16(v0, v1);
                int c0 = w * 32 + l15;
                s.h[rl * HSTR + c0]      = (unsigned short)pk;
                s.h[rl * HSTR + c0 + 16] = (unsigned short)(pk >> 16);
            }
    }
    __syncthreads();

    // stage 2: h1o = relu(GN(feat@fc1_0))
    f32x4 accC[2][2] = {};
    gemm_lds(accC, s, f1T, 128, 0, 4, w, l15, lhi);
    gn_stats(s, accC, w, l15, lhi, tid);           // ends with barrier
    vec_out(s.h, fbf, rowbase, nrows, tid);        // feat writeout (s.h intact)
    {
        float gv[2], bv[2];
        #pragma unroll
        for (int ni = 0; ni < 2; ++ni) {
            int col = w * 32 + ni * 16 + l15;
            gv[ni] = g1n[col]; bv[ni] = b1n[col];
        }
        #pragma unroll
        for (int mi = 0; mi < 2; ++mi)
            #pragma unroll
            for (int j = 0; j < 4; ++j) {
                int rl = mi * 16 + lhi * 4 + j;
                float mean = s.mv[rl][0], rstd = s.mv[rl][1];
                float v0 = fmaxf((accC[mi][0][j] - mean) * rstd * gv[0] + bv[0], 0.f);
                float v1 = fmaxf((accC[mi][1][j] - mean) * rstd * gv[1] + bv[1], 0.f);
                unsigned pk = cvt_pk_bf16(v0, v1);
                int c0 = w * 32 + l15;
                s.res[rl * HSTR + c0]      = (unsigned short)pk;
                s.res[rl * HSTR + c0 + 16] = (unsigned short)(pk >> 16);
            }
    }
    __syncthreads();
    vec_out_chunk(s.res, h1bf, rowbase, nrows, tid, nrows);  // h1 (chunked)
}

// ---------------------------------------------------------------------------
// one agg block (minus seg_max), M=32 tile, LDS residual + vector IO
__global__ __launch_bounds__(256) void block_fused(
    unsigned short* __restrict__ fbf,
    const unsigned short* __restrict__ aggbf,
    const unsigned short* __restrict__ wts, int kblk,
    const float* __restrict__ g2, const float* __restrict__ b2,
    const float* __restrict__ gl, const float* __restrict__ bl,
    const float* __restrict__ g1n, const float* __restrict__ b1n,
    unsigned short* __restrict__ h1bf, float* __restrict__ outf,
    int nrows, int has_next)
{
    __shared__ FSmem s;
    const int tid = threadIdx.x;
    const int w = tid >> 6, l = tid & 63, l15 = l & 15, lhi = l >> 4;
    const int rowbase = blockIdx.x * 32;

    const unsigned short* fc2T = wts + 90112 + (size_t)kblk * 32768;   // K=256
    const unsigned short* linT = wts + 221184 + (size_t)kblk * 16384;  // K=128
    const unsigned short* f1T  = wts + 24576 + (size_t)(kblk + 1) * 16384;

    // stage 1: h = relu(GN([feat|agg]@fc2)); feat tile stashed -> s.res
    f32x4 acc2[2][2] = {};
    gemm_fc2(acc2, s, fbf, aggbf, fc2T, rowbase, w, l15, lhi);
    gn_stats(s, acc2, w, l15, lhi, tid);
    epi_lds(acc2, s, g2, b2, w, l15, lhi);
    __syncthreads();

    // stage 2: nf = relu(GN(h@lin) + feat)  (residual from s.res)
    f32x4 acc3[2][2] = {};
    gemm_lds(acc3, s, linT, 128, 0, 4, w, l15, lhi);
    gn_stats(s, acc3, w, l15, lhi, tid);
    {
        float gv[2], bv[2];
        #pragma unroll
        for (int ni = 0; ni < 2; ++ni) {
            int col = w * 32 + ni * 16 + l15;
            gv[ni] = gl[col]; bv[ni] = bl[col];
        }
        #pragma unroll
        for (int mi = 0; mi < 2; ++mi)
            #pragma unroll
            for (int j = 0; j < 4; ++j) {
                int rl = mi * 16 + lhi * 4 + j;
                int row = rowbase + rl;
                float mean = s.mv[rl][0], rstd = s.mv[rl][1];
                int c0 = w * 32 + l15;
                float v0 = (acc3[mi][0][j] - mean) * rstd * gv[0] + bv[0]
                         + bf2f(s.res[rl * HSTR + c0]);
                float v1 = (acc3[mi][1][j] - mean) * rstd * gv[1] + bv[1]
                         + bf2f(s.res[rl * HSTR + c0 + 16]);
                v0 = fmaxf(v0, 0.f); v1 = fmaxf(v1, 0.f);
                unsigned pk = cvt_pk_bf16(v0, v1);
                s.h[rl * HSTR + c0]      = (unsigned short)pk;
                s.h[rl * HSTR + c0 + 16] = (unsigned short)(pk >> 16);
                if (outf && row < nrows) {
                    outf[(size_t)row * NMAP + c0]      = v0;
                    outf[(size_t)row * NMAP + c0 + 16] = v1;
                }
            }
    }

    // stage 3: h1o = relu(GN(nf@fc1_next)); vectorized writeouts
    if (has_next) {
        __syncthreads();
        f32x4 acc4[2][2] = {};
        gemm_lds(acc4, s, f1T, 128, 0, 4, w, l15, lhi);
        gn_stats(s, acc4, w, l15, lhi, tid);       // ends with barrier
        vec_out(s.h, fbf, rowbase, nrows, tid);    // nf -> fbf (s.h intact)
        {
            float gv[2], bv[2];
            #pragma unroll
            for (int ni = 0; ni < 2; ++ni) {
                int col = w * 32 + ni * 16 + l15;
                gv[ni] = g1n[col]; bv[ni] = b1n[col];
            }
            #pragma unroll
            for (int mi = 0; mi < 2; ++mi)
                #pragma unroll
                for (int j = 0; j < 4; ++j) {
                    int rl = mi * 16 + lhi * 4 + j;
                    float mean = s.mv[rl][0], rstd = s.mv[rl][1];
                    float v0 = fmaxf((acc4[mi][0][j] - mean) * rstd * gv[0] + bv[0], 0.f);
                    float v1 = fmaxf((acc4[mi][1][j] - mean) * rstd * gv[1] + bv[1], 0.f);
                    unsigned pk = cvt_pk_bf16(v0, v1);
                    int c0 = w * 32 + l15;
                    s.res[rl * HSTR + c0]      = (unsigned short)pk;
                    s.res[rl * HSTR + c0 + 16] = (unsigned short)(pk >> 16);
                }
        }
        __syncthreads();
        vec_out_chunk(s.res, h1bf, rowbase, nrows, tid, nrows);  // h1o (chunked)
    }
}

// ---------------------------------------------------------------------------
// all weight converts in one kernel.  wts layout (shorts):
//   w1T@0(4096) wtT@4096(4096) w2T@8192(16384) fc1T@24576(65536)
//   fc2T@90112(131072) linT@221184(65536)  total 286720
__global__ __launch_bounds__(256) void cvt_all_w(
    const float* __restrict__ in_w1, const float* __restrict__ in_wt,
    const float* __restrict__ in_w2, const float* __restrict__ fc1_w,
    const float* __restrict__ fc2_w, const float* __restrict__ lin_w,
    unsigned short* __restrict__ wts)
{
    int idx = blockIdx.x * 256 + threadIdx.x;
    if (idx >= 286720) return;
    const float* src; int off, K, Kreal;
    if (idx < 4096)        { src = in_w1; off = idx;          K = 32;  Kreal = 22; }
    else if (idx < 8192)   { src = in_wt; off = idx - 4096;   K = 32;  Kreal = 22; }
    else if (idx < 24576)  { src = in_w2; off = idx - 8192;   K = 128; Kreal = 128; }
    else if (idx < 90112)  { src = fc1_w; off = idx - 24576;  K = 128; Kreal = 128; }
    else if (idx < 221184) { src = fc2_w; off = idx - 90112;  K = 256; Kreal = 256; }
    else                   { src = lin_w; off = idx - 221184; K = 128; Kreal = 128; }
    int per = 128 * K;
    int m = off / per, rem = off - m * per;
    int c = rem / K, k = rem - c * K;
    float val = (k < Kreal) ? src[(size_t)m * per + (size_t)k * 128 + c] : 0.f;
    wts[idx] = f2bf(val);
}

// feats fp32 [N][22] -> bf16 [N+64][32] zero-padded
__global__ __launch_bounds__(256) void cvt_feats_kernel(
    const float* __restrict__ src, unsigned short* __restrict__ dst, int N)
{
    int idx = blockIdx.x * 256 + threadIdx.x;
    int n = idx >> 5, kk = idx & 31;
    if (n < N + 64) {
        float v = (n < N && kk < 22) ? src[(size_t)n * 22 + kk] : 0.f;
        dst[idx] = f2bf(v);
    }
}

// ---------------- CSR build: both scales fused per phase -------------------
__global__ __launch_bounds__(256) void hist2_kernel(
    const int* __restrict__ v, int* __restrict__ rp, int E, int N)
{
    int e = blockIdx.x * 256 + threadIdx.x;
    if (e < 2 * E) {
        int sc = e >= E;
        atomicAdd(&rp[sc * (N + 1) + v[e] + 1], 1);
    }
}

__global__ __launch_bounds__(256) void scan1_kernel(
    int* __restrict__ rp, int* __restrict__ part, int n1, int NB)
{
    __shared__ int wtot[4];
    const int sc = blockIdx.x / NB, chunk = blockIdx.x - sc * NB;
    int* data = rp + (size_t)sc * n1;
    const int tid = threadIdx.x;
    const int base = chunk * SCHUNK + tid * 8;
    int vv[8];
    #pragma unroll
    for (int i = 0; i < 8; ++i) {
        int idx = base + i;
        vv[i] = (idx < n1) ? data[idx] : 0;
    }
    #pragma unroll
    for (int i = 1; i < 8; ++i) vv[i] += vv[i - 1];
    int tsum = vv[7];
    const int lane = tid & 63, wid = tid >> 6;
    int scn = tsum;
    #pragma unroll
    for (int d = 1; d < 64; d <<= 1) {
        int t = __shfl_up(scn, d);
        if (lane >= d) scn += t;
    }
    if (lane == 63) wtot[wid] = scn;
    __syncthreads();
    int woff = 0;
    for (int w2 = 0; w2 < wid; ++w2) woff += wtot[w2];
    const int excl = scn - tsum + woff;
    #pragma unroll
    for (int i = 0; i < 8; ++i) {
        int idx = base + i;
        if (idx < n1) data[idx] = vv[i] + excl;
    }
    if (tid == 255) part[blockIdx.x] = excl + tsum;
}

__global__ __launch_bounds__(256) void scan2_kernel(int* part, int NB)
{
    __shared__ int wsum[4];
    int* data = part + blockIdx.x * NB;
    const int tid = threadIdx.x;
    const int lane = tid & 63, wid = tid >> 6;
    int carry = 0;
    for (int base = 0; base < NB; base += 256) {
        int i = base + tid;
        int val = (i < NB) ? data[i] : 0;
        #pragma unroll
        for (int d = 1; d < 64; d <<= 1) {
            int t = __shfl_up(val, d);
            if (lane >= d) val += t;
        }
        if (lane == 63) wsum[wid] = val;
        __syncthreads();
        int woff = 0;
        for (int w = 0; w < wid; ++w) woff += wsum[w];
        int total = wsum[0] + wsum[1] + wsum[2] + wsum[3];
        val += woff + carry;
        if (i < NB) data[i] = val;
        __syncthreads();
        carry += total;
    }
}

__global__ __launch_bounds__(256) void scan3_kernel(
    int* __restrict__ rp, const int* __restrict__ part, int n1, int NB)
{
    const int nbm1 = NB - 1;
    const int sc = blockIdx.x / nbm1, i = blockIdx.x - sc * nbm1;
    int* data = rp + (size_t)sc * n1;
    const int base = (i + 1) * SCHUNK + threadIdx.x * 8;
    const int off = part[sc * NB + i];
    #pragma unroll
    for (int q = 0; q < 8; ++q) {
        int idx = base + q;
        if (idx < n1) data[idx] += off;
    }
}

// gcur[bk] = sc*E + rp[sc][min(b*256, N)]
__global__ __launch_bounds__(256) void init_gcur(
    const int* __restrict__ rp, int* __restrict__ gcur, int E, int N, int nbk)
{
    int i = blockIdx.x * 256 + threadIdx.x;
    if (i < 2 * nbk) {
        int sc = i >= nbk;
        int b = i - sc * nbk;
        int nb0 = b << BKSH; if (nb0 > N) nb0 = N;
        gcur[i] = sc * E + rp[sc * (N + 1) + nb0];
    }
}

// pass 1: scatter (u,v) pairs into bucket regions (bucket = 256-node range)
__global__ __launch_bounds__(256) void bucket_scatter(
    const int* __restrict__ u, const int* __restrict__ v,
    int* __restrict__ gcur, int2* __restrict__ pairs, int E, int nbk)
{
    __shared__ int cnt[1024], base[1024];
    const int tid = threadIdx.x;
    const int tot = 2 * E;
    const int c0 = blockIdx.x * CH;
    const int nbk2 = 2 * nbk;
    for (int i = tid; i < nbk2; i += 256) cnt[i] = 0;
    __syncthreads();
    for (int i = 0; i < CH; i += 256) {
        int e = c0 + i + tid;
        if (e < tot) {
            int sc = e >= E;
            int vv = v[e];
            atomicAdd(&cnt[sc * nbk + (vv >> BKSH)], 1);
        }
    }
    __syncthreads();
    for (int i = tid; i < nbk2; i += 256) {
        int c = cnt[i];
        base[i] = c ? atomicAdd(&gcur[i], c) : 0;
        cnt[i] = 0;
    }
    __syncthreads();
    for (int i = 0; i < CH; i += 256) {
        int e = c0 + i + tid;
        if (e < tot) {
            int sc = e >= E;
            int uu = u[e], vv = v[e];
            int bk = sc * nbk + (vv >> BKSH);
            int off = atomicAdd(&cnt[bk], 1);
            pairs[(size_t)base[bk] + off] = make_int2(uu, vv);
        }
    }
}

// pass 2: per-bucket scatter into final CSR order (writes stay in ~10KB region)
__global__ __launch_bounds__(256) void bucket_fill(
    const int2* __restrict__ pairs, const int* __restrict__ rp,
    int* __restrict__ su, int E, int N, int nbk)
{
    __shared__ int curs[256];
    const int bk = blockIdx.x;
    const int sc = bk >= nbk;
    const int b = bk - sc * nbk;
    const int nb0 = b << BKSH;
    const int nb1 = min(nb0 + (1 << BKSH), N);
    const int nn = nb1 - nb0;
    const int* rps = rp + (size_t)sc * (N + 1);
    const int tid = threadIdx.x;
    const int rstart = rps[nb0], rend = rps[nb1];
    if (tid < nn) curs[tid] = rps[nb0 + tid];
    __syncthreads();
    int* sus = su + (size_t)sc * E;
    for (int idx = rstart + tid; idx < rend; idx += 256) {
        int2 pr = pairs[(size_t)sc * E + idx];
        int pos = atomicAdd(&curs[pr.y - nb0], 1);
        sus[pos] = pr.x;
    }
}

// chunked seg_max: h1c layout [8][N][16ch] (uint view [8][N][8]).
// grid = 8 chunks x ceil(N/32) blocks (chunk-major order -> per-XCD L2 holds
// the live 3.2 MB chunk). 8 lanes per node, 4 B/lane, 4-deep unrolled gather.
__global__ __launch_bounds__(256) void seg_max_chunk(
    const int* __restrict__ rp, const int* __restrict__ su,
    const unsigned* __restrict__ h1c, unsigned* __restrict__ agg,
    int N, int NBn)
{
    const int chunk = blockIdx.x / NBn;
    const int nb = blockIdx.x - chunk * NBn;
    const int node = nb * 32 + (threadIdx.x >> 3);
    const int g = threadIdx.x & 7;
    if (node >= N) return;
    const unsigned* hc = h1c + (size_t)chunk * N * 8;
    int s0 = rp[node], e0 = rp[node + 1];
    unsigned lo[4] = {0,0,0,0}, hi[4] = {0,0,0,0};
    int j = s0;
    for (; j + 3 < e0; j += 4) {
        unsigned x[4];
        #pragma unroll
        for (int q = 0; q < 4; ++q) x[q] = hc[(size_t)su[j + q] * 8 + g];
        #pragma unroll
        for (int q = 0; q < 4; ++q) {
            lo[q] = max(lo[q], x[q] & 0xffffu);
            hi[q] = max(hi[q], x[q] >> 16);
        }
    }
    for (; j < e0; ++j) {
        unsigned x0 = hc[(size_t)su[j] * 8 + g];
        lo[0] = max(lo[0], x0 & 0xffffu); hi[0] = max(hi[0], x0 >> 16);
    }
    lo[0] = max(max(lo[0], lo[1]), max(lo[2], lo[3]));
    hi[0] = max(max(hi[0], hi[1]), max(hi[2], hi[3]));
    agg[(size_t)node * 64 + chunk * 8 + g] = lo[0] | (hi[0] << 16);
}

// ---------------------------------------------------------------------------
extern "C" void kernel_launch(void* const* d_in, const int* in_sizes, int n_in,
                              void* d_out, int out_size, void* d_ws, size_t ws_size,
                              hipStream_t stream)
{
    const float* feats = (const float*)d_in[0];
    const int*   u     = (const int*)d_in[1];
    const int*   v     = (const int*)d_in[2];
    const float* in_w1 = (const float*)d_in[3];
    const float* in_g1 = (const float*)d_in[4];
    const float* in_b1 = (const float*)d_in[5];
    const float* in_w2 = (const float*)d_in[6];
    const float* in_g2 = (const float*)d_in[7];
    const float* in_b2 = (const float*)d_in[8];
    const float* in_wt = (const float*)d_in[9];
    const float* in_gt = (const float*)d_in[10];
    const float* in_bt = (const float*)d_in[11];
    const float* fc1_w = (const float*)d_in[12];
    const float* fc1_g = (const float*)d_in[13];
    const float* fc1_b = (const float*)d_in[14];
    const float* fc2_w = (const float*)d_in[15];
    const float* fc2_g = (const float*)d_in[16];
    const float* fc2_b = (const float*)d_in[17];
    const float* lin_w = (const float*)d_in[18];
    const float* lin_g = (const float*)d_in[19];
    const float* lin_b = (const float*)d_in[20];

    const int N = in_sizes[0] / 22;
    const int E = in_sizes[1] / 2;
    const size_t nmp = (size_t)(N + 64) * NMAP;

    unsigned short* fbf   = (unsigned short*)d_ws;     // running feat (row-major)
    unsigned short* h1bf  = fbf + nmp;                 // h1 (chunk-major [8][N][16])
    unsigned short* aggbf = h1bf + nmp;                // agg (row-major)
    unsigned short* x32   = aggbf + nmp;               // padded input feats
    unsigned short* wts   = x32 + (size_t)(N + 64) * 32;
    unsigned short* wend  = wts + 286720;

    int* rp   = (int*)wend;          // 2*(N+1)
    int* su   = rp + 2 * (N + 1);    // 2*E
    int* part = su + 2 * (size_t)E;  // scan partials (<=128)
    int* gcur = part + 256;          // 2*nbk (<=1024)
    int2* pairs = (int2*)aggbf;      // 16 MB; aggbf free until first seg_max

    const int nbk = (N + (1 << BKSH) - 1) >> BKSH;     // buckets per scale

    // ---- one-time converts ----
    cvt_feats_kernel<<<((N + 64) * 32 + 255) / 256, 256, 0, stream>>>(feats, x32, N);
    cvt_all_w<<<(286720 + 255) / 256, 256, 0, stream>>>(
        in_w1, in_wt, in_w2, fc1_w, fc2_w, lin_w, wts);

    // ---- one-time CSR build ----
    {
        const int n1 = N + 1;
        const int NB = (n1 + SCHUNK - 1) / SCHUNK;
        hipMemsetAsync(rp, 0, 2 * (size_t)n1 * sizeof(int), stream);
        hist2_kernel<<<(2 * E + 255) / 256, 256, 0, stream>>>(v, rp, E, N);
        scan1_kernel<<<2 * NB, 256, 0, stream>>>(rp, part, n1, NB);
        scan2_kernel<<<2, 256, 0, stream>>>(part, NB);
        scan3_kernel<<<2 * (NB - 1), 256, 0, stream>>>(rp, part, n1, NB);
        init_gcur<<<(2 * nbk + 255) / 256, 256, 0, stream>>>(rp, gcur, E, N, nbk);
        bucket_scatter<<<(2 * E + CH - 1) / CH, 256, 0, stream>>>(
            u, v, gcur, pairs, E, nbk);
        bucket_fill<<<2 * nbk, 256, 0, stream>>>(pairs, rp, su, E, N, nbk);
    }

    const int GB = (N + 31) / 32;          // tile blocks
    const int NBn = (N + 31) / 32;         // seg_max node-blocks per chunk

    // ---- input stage + fc1[0] ----
    input_fused<<<GB, 256, 0, stream>>>(x32, wts,
        in_g1, in_b1, in_gt, in_bt, in_g2, in_b2,
        fc1_g, fc1_b, fbf, h1bf, N);

    // ---- agg blocks ----
    for (int k = 0; k < 4; ++k) {
        int is = k & 1;
        int has_next = (k < 3);
        seg_max_chunk<<<8 * NBn, 256, 0, stream>>>(rp + (size_t)is * (N + 1),
            su + (size_t)is * E, (const unsigned*)h1bf, (unsigned*)aggbf, N, NBn);
        block_fused<<<GB, 256, 0, stream>>>(fbf, aggbf, wts, k,
            fc2_g + k * 128, fc2_b + k * 128,
            lin_g + k * 128, lin_b + k * 128,
            has_next ? fc1_g + (k + 1) * 128 : nullptr,
            has_next ? fc1_b + (k + 1) * 128 : nullptr,
            h1bf, (k == 3) ? (float*)d_out : nullptr, N, has_next);
    }
}

// Round 15
// 618.911 us; speedup vs baseline: 1.3198x; 1.3198x over previous
//
#include <hip/hip_runtime.h>

#define NMAP 128
#define EPSV 1e-5f
#define SCHUNK 2048     // elements per scan block (256 thr x 8)
#define HSTR 136        // LDS h-tile row stride in shorts (272 B)
#define BKSH 8          // 256 nodes per bucket
#define CH 8192         // edges per bucket_scatter workgroup

typedef __attribute__((ext_vector_type(8))) short bf16x8;   // 8 bf16 = 4 VGPRs
typedef __attribute__((ext_vector_type(4))) float f32x4;

__device__ __forceinline__ unsigned short f2bf(float f) {
    union { float f; unsigned u; } x; x.f = f;
    unsigned u = x.u;
    return (unsigned short)((u + 0x7fffu + ((u >> 16) & 1u)) >> 16);  // RNE
}
__device__ __forceinline__ float bf2f(unsigned short h) {
    union { unsigned u; float f; } x; x.u = ((unsigned)h) << 16;
    return x.f;
}
// two f32 -> packed bf16 pair (RNE, same rounding as f2bf), 1 VALU op
__device__ __forceinline__ unsigned cvt_pk_bf16(float lo, float hi) {
    unsigned r;
    asm("v_cvt_pk_bf16_f32 %0, %1, %2" : "=v"(r) : "v"(lo), "v"(hi));
    return r;
}
// packed u16 max (valid bf16 max for non-negative values)
__device__ __forceinline__ unsigned pkmax(unsigned a, unsigned b) {
    unsigned r;
    asm("v_pk_max_u16 %0, %1, %2" : "=v"(r) : "v"(a), "v"(b));
    return r;
}
__device__ __forceinline__ uint4 pkmax4(uint4 a, uint4 b) {
    return make_uint4(pkmax(a.x, b.x), pkmax(a.y, b.y),
                      pkmax(a.z, b.z), pkmax(a.w, b.w));
}

// M=32 tile: 4 waves; wave w -> cols [w*32,(w+1)*32), 2x2 fragments.
// row = mi*16 + lhi*4 + j (mi<2), col = w*32 + ni*16 + l15 (ni<2).
struct __align__(16) FSmem {
    unsigned short h[32 * HSTR];    // 8704 B  bf16 h-tile [32][136]
    unsigned short res[32 * HSTR];  // 8704 B  residual / h1o staging tile
    float2 red[4][4][34];           // 4352 B  GN partials [w][cg][row], (sum,ss)
    float mv[32][2];                //  256 B  mean/rstd per row
};

// per-row mean/rstd over 128 cols -> s.mv  (2 shfl stages + packed LDS finish)
__device__ __forceinline__ void gn_stats(FSmem& s, const f32x4 acc[2][2],
                                         int w, int l15, int lhi, int tid)
{
    const int cg = l15 >> 2;
    #pragma unroll
    for (int mi = 0; mi < 2; ++mi) {
        #pragma unroll
        for (int j = 0; j < 4; ++j) {
            float a0 = acc[mi][0][j], a1 = acc[mi][1][j];
            float s0 = a0 + a1, s1 = a0 * a0 + a1 * a1;
            s0 += __shfl_xor(s0, 1); s1 += __shfl_xor(s1, 1);
            s0 += __shfl_xor(s0, 2); s1 += __shfl_xor(s1, 2);
            if ((l15 & 3) == 0) {
                int row = mi * 16 + lhi * 4 + j;
                s.red[w][cg][row] = make_float2(s0, s1);
            }
        }
    }
    __syncthreads();
    if (tid < 32) {
        float sm = 0.f, ss = 0.f;
        #pragma unroll
        for (int ww = 0; ww < 4; ++ww)
            #pragma unroll
            for (int cgg = 0; cgg < 4; ++cgg) {
                float2 p = s.red[ww][cgg][tid];
                sm += p.x; ss += p.y;
            }
        float mean = sm * (1.f / 128.f);
        float var = ss * (1.f / 128.f) - mean * mean;
        s.mv[tid][0] = mean;
        s.mv[tid][1] = rsqrtf(var + EPSV);
    }
    __syncthreads();
}

// acc += h_lds @ WT[kwoff..]   (A from s.h, B loaded inline)
__device__ __forceinline__ void gemm_lds(f32x4 acc[2][2], const FSmem& s,
    const unsigned short* __restrict__ WT, int K, int kwoff, int nks,
    int w, int l15, int lhi)
{
    #pragma unroll
    for (int ks = 0; ks < nks; ++ks) {
        bf16x8 af[2], bfr[2];
        #pragma unroll
        for (int mi = 0; mi < 2; ++mi)
            af[mi] = *(const bf16x8*)&s.h[(mi * 16 + l15) * HSTR + ks * 32 + lhi * 8];
        #pragma unroll
        for (int ni = 0; ni < 2; ++ni)
            bfr[ni] = *(const bf16x8*)&WT[(size_t)(w * 32 + ni * 16 + l15) * K + kwoff + ks * 32 + lhi * 8];
        #pragma unroll
        for (int mi = 0; mi < 2; ++mi)
            #pragma unroll
            for (int ni = 0; ni < 2; ++ni)
                acc[mi][ni] = __builtin_amdgcn_mfma_f32_16x16x32_bf16(
                    af[mi], bfr[ni], acc[mi][ni], 0, 0, 0);
    }
}

// acc += Xf @ WT[cols 0..128) of K=256; wave 0 stashes Xf tile -> s.res
__device__ __forceinline__ void gemm_feat_stash(f32x4 acc[2][2], FSmem& s,
    const unsigned short* __restrict__ Xf,
    const unsigned short* __restrict__ WT,
    int rowbase, int w, int l15, int lhi)
{
    #pragma unroll
    for (int ks = 0; ks < 4; ++ks) {
        bf16x8 af[2], bfr[2];
        #pragma unroll
        for (int mi = 0; mi < 2; ++mi)
            af[mi] = *(const bf16x8*)&Xf[(size_t)(rowbase + mi * 16 + l15) * 128 + ks * 32 + lhi * 8];
        if (w == 0) {
            #pragma unroll
            for (int mi = 0; mi < 2; ++mi)
                *(bf16x8*)&s.res[(mi * 16 + l15) * HSTR + ks * 32 + lhi * 8] = af[mi];
        }
        #pragma unroll
        for (int ni = 0; ni < 2; ++ni)
            bfr[ni] = *(const bf16x8*)&WT[(size_t)(w * 32 + ni * 16 + l15) * 256 + ks * 32 + lhi * 8];
        #pragma unroll
        for (int mi = 0; mi < 2; ++mi)
            #pragma unroll
            for (int ni = 0; ni < 2; ++ni)
                acc[mi][ni] = __builtin_amdgcn_mfma_f32_16x16x32_bf16(
                    af[mi], bfr[ni], acc[mi][ni], 0, 0, 0);
    }
}

// GN + relu -> s.h  (cvt_pk pairs the two ni columns)
__device__ __forceinline__ void epi_lds(const f32x4 acc[2][2], FSmem& s,
    const float* __restrict__ g, const float* __restrict__ b, int w, int l15, int lhi)
{
    float gv[2], bv[2];
    #pragma unroll
    for (int ni = 0; ni < 2; ++ni) {
        int col = w * 32 + ni * 16 + l15;
        gv[ni] = g[col]; bv[ni] = b[col];
    }
    #pragma unroll
    for (int mi = 0; mi < 2; ++mi)
        #pragma unroll
        for (int j = 0; j < 4; ++j) {
            int row = mi * 16 + lhi * 4 + j;
            float mean = s.mv[row][0], rstd = s.mv[row][1];
            float v0 = fmaxf((acc[mi][0][j] - mean) * rstd * gv[0] + bv[0], 0.f);
            float v1 = fmaxf((acc[mi][1][j] - mean) * rstd * gv[1] + bv[1], 0.f);
            unsigned pk = cvt_pk_bf16(v0, v1);
            int c0 = w * 32 + l15;
            s.h[row * HSTR + c0]      = (unsigned short)pk;
            s.h[row * HSTR + c0 + 16] = (unsigned short)(pk >> 16);
        }
}

// GN in-register (no relu)
__device__ __forceinline__ void norm_reg(f32x4 acc[2][2], const FSmem& s,
    const float* __restrict__ g, const float* __restrict__ b, int w, int l15, int lhi)
{
    float gv[2], bv[2];
    #pragma unroll
    for (int ni = 0; ni < 2; ++ni) {
        int col = w * 32 + ni * 16 + l15;
        gv[ni] = g[col]; bv[ni] = b[col];
    }
    #pragma unroll
    for (int mi = 0; mi < 2; ++mi)
        #pragma unroll
        for (int j = 0; j < 4; ++j) {
            int row = mi * 16 + lhi * 4 + j;
            float mean = s.mv[row][0], rstd = s.mv[row][1];
            #pragma unroll
            for (int ni = 0; ni < 2; ++ni)
                acc[mi][ni][j] = (acc[mi][ni][j] - mean) * rstd * gv[ni] + bv[ni];
        }
}

// vectorized tile writeout: LDS [32][HSTR] -> global row-major [rowbase..][128]
__device__ __forceinline__ void vec_out(const unsigned short* __restrict__ t,
    unsigned short* __restrict__ dst, int rowbase, int nrows, int tid)
{
    #pragma unroll
    for (int it = 0; it < 2; ++it) {
        int c = tid * 2 + it;              // 0..511
        int row = c >> 4, col8 = (c & 15) * 8;
        if (rowbase + row < nrows)
            *(bf16x8*)&dst[(size_t)(rowbase + row) * NMAP + col8] =
                *(const bf16x8*)&t[row * HSTR + col8];
    }
}

// ---------------------------------------------------------------------------
// input stage + first fc1, all fused (M=32 tile)
__global__ __launch_bounds__(256) void input_fused(
    const unsigned short* __restrict__ X32,       // [N+64][32] bf16
    const unsigned short* __restrict__ wts,
    const float* __restrict__ g1, const float* __restrict__ b1,
    const float* __restrict__ gt, const float* __restrict__ bt,
    const float* __restrict__ g2, const float* __restrict__ b2,
    const float* __restrict__ g1n, const float* __restrict__ b1n,
    unsigned short* __restrict__ fbf, unsigned short* __restrict__ h1bf,
    int nrows)
{
    __shared__ FSmem s;
    const int tid = threadIdx.x;
    const int w = tid >> 6, l = tid & 63, l15 = l & 15, lhi = l >> 4;
    const int rowbase = blockIdx.x * 32;

    const unsigned short* w1T = wts;              // K=32
    const unsigned short* wtT = wts + 4096;       // K=32
    const unsigned short* w2T = wts + 8192;       // K=128
    const unsigned short* f1T = wts + 24576;      // fc1[0], K=128

    f32x4 accA[2][2] = {}, accT[2][2] = {};
    {
        bf16x8 af[2], b1f[2], btf[2];
        #pragma unroll
        for (int mi = 0; mi < 2; ++mi)
            af[mi] = *(const bf16x8*)&X32[(size_t)(rowbase + mi * 16 + l15) * 32 + lhi * 8];
        #pragma unroll
        for (int ni = 0; ni < 2; ++ni) {
            int col = w * 32 + ni * 16 + l15;
            b1f[ni] = *(const bf16x8*)&w1T[(size_t)col * 32 + lhi * 8];
            btf[ni] = *(const bf16x8*)&wtT[(size_t)col * 32 + lhi * 8];
        }
        #pragma unroll
        for (int mi = 0; mi < 2; ++mi)
            #pragma unroll
            for (int ni = 0; ni < 2; ++ni) {
                accA[mi][ni] = __builtin_amdgcn_mfma_f32_16x16x32_bf16(af[mi], b1f[ni], accA[mi][ni], 0, 0, 0);
                accT[mi][ni] = __builtin_amdgcn_mfma_f32_16x16x32_bf16(af[mi], btf[ni], accT[mi][ni], 0, 0, 0);
            }
    }

    gn_stats(s, accT, w, l15, lhi, tid);
    norm_reg(accT, s, gt, bt, w, l15, lhi);       // T = GN(X@wt), no relu
    gn_stats(s, accA, w, l15, lhi, tid);
    epi_lds(accA, s, g1, b1, w, l15, lhi);        // h1 -> s.h
    __syncthreads();

    // stage 1: feat = relu(GN(h1@w2) + T) -> s.h only
    f32x4 accB[2][2] = {};
    gemm_lds(accB, s, w2T, 128, 0, 4, w, l15, lhi);
    gn_stats(s, accB, w, l15, lhi, tid);
    {
        float gv[2], bv[2];
        #pragma unroll
        for (int ni = 0; ni < 2; ++ni) {
            int col = w * 32 + ni * 16 + l15;
            gv[ni] = g2[col]; bv[ni] = b2[col];
        }
        #pragma unroll
        for (int mi = 0; mi < 2; ++mi)
            #pragma unroll
            for (int j = 0; j < 4; ++j) {
                int rl = mi * 16 + lhi * 4 + j;
                float mean = s.mv[rl][0], rstd = s.mv[rl][1];
                float v0 = fmaxf((accB[mi][0][j] - mean) * rstd * gv[0] + bv[0]
                                 + accT[mi][0][j], 0.f);
                float v1 = fmaxf((accB[mi][1][j] - mean) * rstd * gv[1] + bv[1]
                                 + accT[mi][1][j], 0.f);
                unsigned pk = cvt_pk_bf16(v0, v1);
                int c0 = w * 32 + l15;
                s.h[rl * HSTR + c0]      = (unsigned short)pk;
                s.h[rl * HSTR + c0 + 16] = (unsigned short)(pk >> 16);
            }
    }
    __syncthreads();

    // stage 2: h1o = relu(GN(feat@fc1_0))
    f32x4 accC[2][2] = {};
    gemm_lds(accC, s, f1T, 128, 0, 4, w, l15, lhi);
    gn_stats(s, accC, w, l15, lhi, tid);           // ends with barrier
    vec_out(s.h, fbf, rowbase, nrows, tid);        // feat writeout (s.h intact)
    {
        float gv[2], bv[2];
        #pragma unroll
        for (int ni = 0; ni < 2; ++ni) {
            int col = w * 32 + ni * 16 + l15;
            gv[ni] = g1n[col]; bv[ni] = b1n[col];
        }
        #pragma unroll
        for (int mi = 0; mi < 2; ++mi)
            #pragma unroll
            for (int j = 0; j < 4; ++j) {
                int rl = mi * 16 + lhi * 4 + j;
                float mean = s.mv[rl][0], rstd = s.mv[rl][1];
                float v0 = fmaxf((accC[mi][0][j] - mean) * rstd * gv[0] + bv[0], 0.f);
                float v1 = fmaxf((accC[mi][1][j] - mean) * rstd * gv[1] + bv[1], 0.f);
                unsigned pk = cvt_pk_bf16(v0, v1);
                int c0 = w * 32 + l15;
                s.res[rl * HSTR + c0]      = (unsigned short)pk;
                s.res[rl * HSTR + c0 + 16] = (unsigned short)(pk >> 16);
            }
    }
    __syncthreads();
    vec_out(s.res, h1bf, rowbase, nrows, tid);     // h1 writeout (row-major)
}

// ---------------------------------------------------------------------------
// one agg block WITH fused seg-max gather (stage 0), M=32 tile:
//   agg(s.h) = segmax(h1in[in-edges]); h = relu(GN([feat|agg]@fc2));
//   nf = relu(GN(h@lin)+feat); feat<-nf; h1out = relu(GN(nf@fc1_next))
// Gather: 8 lanes/node, all 32 nodes parallel, 2-edge unroll, pk_max_u16.
__global__ __launch_bounds__(256) void block_fused(
    unsigned short* __restrict__ fbf,
    const int* __restrict__ rp, const int* __restrict__ su,
    const unsigned* __restrict__ h1in,            // u32 view, 64 uints/row
    const unsigned short* __restrict__ wts, int kblk,
    const float* __restrict__ g2, const float* __restrict__ b2,
    const float* __restrict__ gl, const float* __restrict__ bl,
    const float* __restrict__ g1n, const float* __restrict__ b1n,
    unsigned short* __restrict__ h1out, float* __restrict__ outf,
    int nrows, int has_next)
{
    __shared__ FSmem s;
    const int tid = threadIdx.x;
    const int w = tid >> 6, l = tid & 63, l15 = l & 15, lhi = l >> 4;
    const int rowbase = blockIdx.x * 32;

    const unsigned short* fc2T = wts + 90112 + (size_t)kblk * 32768;   // K=256
    const unsigned short* linT = wts + 221184 + (size_t)kblk * 16384;  // K=128
    const unsigned short* f1T  = wts + 24576 + (size_t)(kblk + 1) * 16384;

    // ---- stage 0: parallel seg-max gather -> s.h (agg tile) ----
    {
        const int node8 = tid >> 3, g = tid & 7;
        const int node = rowbase + node8;
        uint4 A0 = make_uint4(0, 0, 0, 0), A1 = make_uint4(0, 0, 0, 0);
        if (node < nrows) {
            int j = rp[node], e0 = rp[node + 1];
            for (; j + 1 < e0; j += 2) {
                const uint4* r0 = (const uint4*)&h1in[(size_t)su[j] * 64 + g * 8];
                const uint4* r1 = (const uint4*)&h1in[(size_t)su[j + 1] * 64 + g * 8];
                uint4 x0 = r0[0], x1 = r0[1];
                uint4 y0 = r1[0], y1 = r1[1];
                A0 = pkmax4(A0, x0); A1 = pkmax4(A1, x1);
                A0 = pkmax4(A0, y0); A1 = pkmax4(A1, y1);
            }
            if (j < e0) {
                const uint4* r0 = (const uint4*)&h1in[(size_t)su[j] * 64 + g * 8];
                A0 = pkmax4(A0, r0[0]); A1 = pkmax4(A1, r0[1]);
            }
        }
        *(uint4*)&s.h[node8 * HSTR + g * 16]     = A0;
        *(uint4*)&s.h[node8 * HSTR + g * 16 + 8] = A1;
    }
    __syncthreads();

    // ---- stage 1: h = relu(GN([feat|agg]@fc2)); feat tile stashed -> s.res ----
    f32x4 acc2[2][2] = {};
    gemm_feat_stash(acc2, s, fbf, fc2T, rowbase, w, l15, lhi);   // feat half
    gemm_lds(acc2, s, fc2T, 256, 128, 4, w, l15, lhi);           // agg half (LDS)
    gn_stats(s, acc2, w, l15, lhi, tid);      // barriers: s.h reads complete
    epi_lds(acc2, s, g2, b2, w, l15, lhi);    // overwrite s.h with h
    __syncthreads();

    // ---- stage 2: nf = relu(GN(h@lin) + feat)  (residual from s.res) ----
    f32x4 acc3[2][2] = {};
    gemm_lds(acc3, s, linT, 128, 0, 4, w, l15, lhi);
    gn_stats(s, acc3, w, l15, lhi, tid);
    {
        float gv[2], bv[2];
        #pragma unroll
        for (int ni = 0; ni < 2; ++ni) {
            int col = w * 32 + ni * 16 + l15;
            gv[ni] = gl[col]; bv[ni] = bl[col];
        }
        #pragma unroll
        for (int mi = 0; mi < 2; ++mi)
            #pragma unroll
            for (int j = 0; j < 4; ++j) {
                int rl = mi * 16 + lhi * 4 + j;
                int row = rowbase + rl;
                float mean = s.mv[rl][0], rstd = s.mv[rl][1];
                int c0 = w * 32 + l15;
                float v0 = (acc3[mi][0][j] - mean) * rstd * gv[0] + bv[0]
                         + bf2f(s.res[rl * HSTR + c0]);
                float v1 = (acc3[mi][1][j] - mean) * rstd * gv[1] + bv[1]
                         + bf2f(s.res[rl * HSTR + c0 + 16]);
                v0 = fmaxf(v0, 0.f); v1 = fmaxf(v1, 0.f);
                unsigned pk = cvt_pk_bf16(v0, v1);
                s.h[rl * HSTR + c0]      = (unsigned short)pk;
                s.h[rl * HSTR + c0 + 16] = (unsigned short)(pk >> 16);
                if (outf && row < nrows) {
                    outf[(size_t)row * NMAP + c0]      = v0;
                    outf[(size_t)row * NMAP + c0 + 16] = v1;
                }
            }
    }

    // ---- stage 3: h1out = relu(GN(nf@fc1_next)); vectorized writeouts ----
    if (has_next) {
        __syncthreads();
        f32x4 acc4[2][2] = {};
        gemm_lds(acc4, s, f1T, 128, 0, 4, w, l15, lhi);
        gn_stats(s, acc4, w, l15, lhi, tid);       // ends with barrier
        vec_out(s.h, fbf, rowbase, nrows, tid);    // nf -> fbf (s.h intact)
        {
            float gv[2], bv[2];
            #pragma unroll
            for (int ni = 0; ni < 2; ++ni) {
                int col = w * 32 + ni * 16 + l15;
                gv[ni] = g1n[col]; bv[ni] = b1n[col];
            }
            #pragma unroll
            for (int mi = 0; mi < 2; ++mi)
                #pragma unroll
                for (int j = 0; j < 4; ++j) {
                    int rl = mi * 16 + lhi * 4 + j;
                    float mean = s.mv[rl][0], rstd = s.mv[rl][1];
                    float v0 = fmaxf((acc4[mi][0][j] - mean) * rstd * gv[0] + bv[0], 0.f);
                    float v1 = fmaxf((acc4[mi][1][j] - mean) * rstd * gv[1] + bv[1], 0.f);
                    unsigned pk = cvt_pk_bf16(v0, v1);
                    int c0 = w * 32 + l15;
                    s.res[rl * HSTR + c0]      = (unsigned short)pk;
                    s.res[rl * HSTR + c0 + 16] = (unsigned short)(pk >> 16);
                }
        }
        __syncthreads();
        vec_out(s.res, h1out, rowbase, nrows, tid); // h1out (row-major)
    }
}

// ---------------------------------------------------------------------------
// all weight converts in one kernel.  wts layout (shorts):
//   w1T@0(4096) wtT@4096(4096) w2T@8192(16384) fc1T@24576(65536)
//   fc2T@90112(131072) linT@221184(65536)  total 286720
__global__ __launch_bounds__(256) void cvt_all_w(
    const float* __restrict__ in_w1, const float* __restrict__ in_wt,
    const float* __restrict__ in_w2, const float* __restrict__ fc1_w,
    const float* __restrict__ fc2_w, const float* __restrict__ lin_w,
    unsigned short* __restrict__ wts)
{
    int idx = blockIdx.x * 256 + threadIdx.x;
    if (idx >= 286720) return;
    const float* src; int off, K, Kreal;
    if (idx < 4096)        { src = in_w1; off = idx;          K = 32;  Kreal = 22; }
    else if (idx < 8192)   { src = in_wt; off = idx - 4096;   K = 32;  Kreal = 22; }
    else if (idx < 24576)  { src = in_w2; off = idx - 8192;   K = 128; Kreal = 128; }
    else if (idx < 90112)  { src = fc1_w; off = idx - 24576;  K = 128; Kreal = 128; }
    else if (idx < 221184) { src = fc2_w; off = idx - 90112;  K = 256; Kreal = 256; }
    else                   { src = lin_w; off = idx - 221184; K = 128; Kreal = 128; }
    int per = 128 * K;
    int m = off / per, rem = off - m * per;
    int c = rem / K, k = rem - c * K;
    float val = (k < Kreal) ? src[(size_t)m * per + (size_t)k * 128 + c] : 0.f;
    wts[idx] = f2bf(val);
}

// feats fp32 [N][22] -> bf16 [N+64][32] zero-padded
__global__ __launch_bounds__(256) void cvt_feats_kernel(
    const float* __restrict__ src, unsigned short* __restrict__ dst, int N)
{
    int idx = blockIdx.x * 256 + threadIdx.x;
    int n = idx >> 5, kk = idx & 31;
    if (n < N + 64) {
        float v = (n < N && kk < 22) ? src[(size_t)n * 22 + kk] : 0.f;
        dst[idx] = f2bf(v);
    }
}

// ---------------- CSR build: both scales fused per phase -------------------
__global__ __launch_bounds__(256) void hist2_kernel(
    const int* __restrict__ v, int* __restrict__ rp, int E, int N)
{
    int e = blockIdx.x * 256 + threadIdx.x;
    if (e < 2 * E) {
        int sc = e >= E;
        atomicAdd(&rp[sc * (N + 1) + v[e] + 1], 1);
    }
}

__global__ __launch_bounds__(256) void scan1_kernel(
    int* __restrict__ rp, int* __restrict__ part, int n1, int NB)
{
    __shared__ int wtot[4];
    const int sc = blockIdx.x / NB, chunk = blockIdx.x - sc * NB;
    int* data = rp + (size_t)sc * n1;
    const int tid = threadIdx.x;
    const int base = chunk * SCHUNK + tid * 8;
    int vv[8];
    #pragma unroll
    for (int i = 0; i < 8; ++i) {
        int idx = base + i;
        vv[i] = (idx < n1) ? data[idx] : 0;
    }
    #pragma unroll
    for (int i = 1; i < 8; ++i) vv[i] += vv[i - 1];
    int tsum = vv[7];
    const int lane = tid & 63, wid = tid >> 6;
    int scn = tsum;
    #pragma unroll
    for (int d = 1; d < 64; d <<= 1) {
        int t = __shfl_up(scn, d);
        if (lane >= d) scn += t;
    }
    if (lane == 63) wtot[wid] = scn;
    __syncthreads();
    int woff = 0;
    for (int w2 = 0; w2 < wid; ++w2) woff += wtot[w2];
    const int excl = scn - tsum + woff;
    #pragma unroll
    for (int i = 0; i < 8; ++i) {
        int idx = base + i;
        if (idx < n1) data[idx] = vv[i] + excl;
    }
    if (tid == 255) part[blockIdx.x] = excl + tsum;
}

__global__ __launch_bounds__(256) void scan2_kernel(int* part, int NB)
{
    __shared__ int wsum[4];
    int* data = part + blockIdx.x * NB;
    const int tid = threadIdx.x;
    const int lane = tid & 63, wid = tid >> 6;
    int carry = 0;
    for (int base = 0; base < NB; base += 256) {
        int i = base + tid;
        int val = (i < NB) ? data[i] : 0;
        #pragma unroll
        for (int d = 1; d < 64; d <<= 1) {
            int t = __shfl_up(val, d);
            if (lane >= d) val += t;
        }
        if (lane == 63) wsum[wid] = val;
        __syncthreads();
        int woff = 0;
        for (int w = 0; w < wid; ++w) woff += wsum[w];
        int total = wsum[0] + wsum[1] + wsum[2] + wsum[3];
        val += woff + carry;
        if (i < NB) data[i] = val;
        __syncthreads();
        carry += total;
    }
}

__global__ __launch_bounds__(256) void scan3_kernel(
    int* __restrict__ rp, const int* __restrict__ part, int n1, int NB)
{
    const int nbm1 = NB - 1;
    const int sc = blockIdx.x / nbm1, i = blockIdx.x - sc * nbm1;
    int* data = rp + (size_t)sc * n1;
    const int base = (i + 1) * SCHUNK + threadIdx.x * 8;
    const int off = part[sc * NB + i];
    #pragma unroll
    for (int q = 0; q < 8; ++q) {
        int idx = base + q;
        if (idx < n1) data[idx] += off;
    }
}

// gcur[bk] = sc*E + rp[sc][min(b*256, N)]
__global__ __launch_bounds__(256) void init_gcur(
    const int* __restrict__ rp, int* __restrict__ gcur, int E, int N, int nbk)
{
    int i = blockIdx.x * 256 + threadIdx.x;
    if (i < 2 * nbk) {
        int sc = i >= nbk;
        int b = i - sc * nbk;
        int nb0 = b << BKSH; if (nb0 > N) nb0 = N;
        gcur[i] = sc * E + rp[sc * (N + 1) + nb0];
    }
}

// pass 1: scatter (u,v) pairs into bucket regions (bucket = 256-node range)
__global__ __launch_bounds__(256) void bucket_scatter(
    const int* __restrict__ u, const int* __restrict__ v,
    int* __restrict__ gcur, int2* __restrict__ pairs, int E, int nbk)
{
    __shared__ int cnt[1024], base[1024];
    const int tid = threadIdx.x;
    const int tot = 2 * E;
    const int c0 = blockIdx.x * CH;
    const int nbk2 = 2 * nbk;
    for (int i = tid; i < nbk2; i += 256) cnt[i] = 0;
    __syncthreads();
    for (int i = 0; i < CH; i += 256) {
        int e = c0 + i + tid;
        if (e < tot) {
            int sc = e >= E;
            int vv = v[e];
            atomicAdd(&cnt[sc * nbk + (vv >> BKSH)], 1);
        }
    }
    __syncthreads();
    for (int i = tid; i < nbk2; i += 256) {
        int c = cnt[i];
        base[i] = c ? atomicAdd(&gcur[i], c) : 0;
        cnt[i] = 0;
    }
    __syncthreads();
    for (int i = 0; i < CH; i += 256) {
        int e = c0 + i + tid;
        if (e < tot) {
            int sc = e >= E;
            int uu = u[e], vv = v[e];
            int bk = sc * nbk + (vv >> BKSH);
            int off = atomicAdd(&cnt[bk], 1);
            pairs[(size_t)base[bk] + off] = make_int2(uu, vv);
        }
    }
}

// pass 2: per-bucket scatter into final CSR order (writes stay in ~10KB region)
__global__ __launch_bounds__(256) void bucket_fill(
    const int2* __restrict__ pairs, const int* __restrict__ rp,
    int* __restrict__ su, int E, int N, int nbk)
{
    __shared__ int curs[256];
    const int bk = blockIdx.x;
    const int sc = bk >= nbk;
    const int b = bk - sc * nbk;
    const int nb0 = b << BKSH;
    const int nb1 = min(nb0 + (1 << BKSH), N);
    const int nn = nb1 - nb0;
    const int* rps = rp + (size_t)sc * (N + 1);
    const int tid = threadIdx.x;
    const int rstart = rps[nb0], rend = rps[nb1];
    if (tid < nn) curs[tid] = rps[nb0 + tid];
    __syncthreads();
    int* sus = su + (size_t)sc * E;
    for (int idx = rstart + tid; idx < rend; idx += 256) {
        int2 pr = pairs[(size_t)sc * E + idx];
        int pos = atomicAdd(&curs[pr.y - nb0], 1);
        sus[pos] = pr.x;
    }
}

// ---------------------------------------------------------------------------
extern "C" void kernel_launch(void* const* d_in, const int* in_sizes, int n_in,
                              void* d_out, int out_size, void* d_ws, size_t ws_size,
                              hipStream_t stream)
{
    const float* feats = (const float*)d_in[0];
    const int*   u     = (const int*)d_in[1];
    const int*   v     = (const int*)d_in[2];
    const float* in_w1 = (const float*)d_in[3];
    const float* in_g1 = (const float*)d_in[4];
    const float* in_b1 = (const float*)d_in[5];
    const float* in_w2 = (const float*)d_in[6];
    const float* in_g2 = (const float*)d_in[7];
    const float* in_b2 = (const float*)d_in[8];
    const float* in_wt = (const float*)d_in[9];
    const float* in_gt = (const float*)d_in[10];
    const float* in_bt = (const float*)d_in[11];
    const float* fc1_w = (const float*)d_in[12];
    const float* fc1_g = (const float*)d_in[13];
    const float* fc1_b = (const float*)d_in[14];
    const float* fc2_w = (const float*)d_in[15];
    const float* fc2_g = (const float*)d_in[16];
    const float* fc2_b = (const float*)d_in[17];
    const float* lin_w = (const float*)d_in[18];
    const float* lin_g = (const float*)d_in[19];
    const float* lin_b = (const float*)d_in[20];

    const int N = in_sizes[0] / 22;
    const int E = in_sizes[1] / 2;
    const size_t nmp = (size_t)(N + 64) * NMAP;

    unsigned short* fbf  = (unsigned short*)d_ws;      // running feat
    unsigned short* h1A  = fbf + nmp;                  // h1 ping
    unsigned short* h1B  = h1A + nmp;                  // h1 pong / pairs scratch
    unsigned short* x32  = h1B + nmp;                  // padded input feats
    unsigned short* wts  = x32 + (size_t)(N + 64) * 32;
    unsigned short* wend = wts + 286720;

    int* rp   = (int*)wend;          // 2*(N+1)
    int* su   = rp + 2 * (N + 1);    // 2*E
    int* part = su + 2 * (size_t)E;  // scan partials (<=128)
    int* gcur = part + 256;          // 2*nbk (<=1024)
    int2* pairs = (int2*)h1B;        // 16 MB; free until first block_fused stage-3

    const int nbk = (N + (1 << BKSH) - 1) >> BKSH;     // buckets per scale

    // ---- one-time converts ----
    cvt_feats_kernel<<<((N + 64) * 32 + 255) / 256, 256, 0, stream>>>(feats, x32, N);
    cvt_all_w<<<(286720 + 255) / 256, 256, 0, stream>>>(
        in_w1, in_wt, in_w2, fc1_w, fc2_w, lin_w, wts);

    // ---- one-time CSR build ----
    {
        const int n1 = N + 1;
        const int NB = (n1 + SCHUNK - 1) / SCHUNK;
        hipMemsetAsync(rp, 0, 2 * (size_t)n1 * sizeof(int), stream);
        hist2_kernel<<<(2 * E + 255) / 256, 256, 0, stream>>>(v, rp, E, N);
        scan1_kernel<<<2 * NB, 256, 0, stream>>>(rp, part, n1, NB);
        scan2_kernel<<<2, 256, 0, stream>>>(part, NB);
        scan3_kernel<<<2 * (NB - 1), 256, 0, stream>>>(rp, part, n1, NB);
        init_gcur<<<(2 * nbk + 255) / 256, 256, 0, stream>>>(rp, gcur, E, N, nbk);
        bucket_scatter<<<(2 * E + CH - 1) / CH, 256, 0, stream>>>(
            u, v, gcur, pairs, E, nbk);
        bucket_fill<<<2 * nbk, 256, 0, stream>>>(pairs, rp, su, E, N, nbk);
    }

    const int GB = (N + 31) / 32;

    // ---- input stage + fc1[0] ----
    input_fused<<<GB, 256, 0, stream>>>(x32, wts,
        in_g1, in_b1, in_gt, in_bt, in_g2, in_b2,
        fc1_g, fc1_b, fbf, h1A, N);

    // ---- agg blocks (seg_max fused; h1 ping-pongs A->B->A->B) ----
    for (int k = 0; k < 4; ++k) {
        int is = k & 1;
        int has_next = (k < 3);
        unsigned short* h1in  = (k & 1) ? h1B : h1A;
        unsigned short* h1out = (k & 1) ? h1A : h1B;
        block_fused<<<GB, 256, 0, stream>>>(fbf,
            rp + (size_t)is * (N + 1), su + (size_t)is * E,
            (const unsigned*)h1in, wts, k,
            fc2_g + k * 128, fc2_b + k * 128,
            lin_g + k * 128, lin_b + k * 128,
            has_next ? fc1_g + (k + 1) * 128 : nullptr,
            has_next ? fc1_b + (k + 1) * 128 : nullptr,
            h1out, (k == 3) ? (float*)d_out : nullptr, N, has_next);
    }
}

// Round 16
// 602.186 us; speedup vs baseline: 1.3565x; 1.0278x over previous
//
#include <hip/hip_runtime.h>

#define NMAP 128
#define EPSV 1e-5f
#define SCHUNK 2048     // elements per scan block (256 thr x 8)
#define HSTR 136        // LDS h-tile row stride in shorts (272 B)
#define BKSH 8          // 256 nodes per bucket
#define CH 8192         // edges per bucket_scatter workgroup

typedef __attribute__((ext_vector_type(8))) short bf16x8;   // 8 bf16 = 4 VGPRs
typedef __attribute__((ext_vector_type(4))) float f32x4;

__device__ __forceinline__ unsigned short f2bf(float f) {
    union { float f; unsigned u; } x; x.f = f;
    unsigned u = x.u;
    return (unsigned short)((u + 0x7fffu + ((u >> 16) & 1u)) >> 16);  // RNE
}
__device__ __forceinline__ float bf2f(unsigned short h) {
    union { unsigned u; float f; } x; x.u = ((unsigned)h) << 16;
    return x.f;
}
// two f32 -> packed bf16 pair (RNE, same rounding as f2bf), 1 VALU op
__device__ __forceinline__ unsigned cvt_pk_bf16(float lo, float hi) {
    unsigned r;
    asm("v_cvt_pk_bf16_f32 %0, %1, %2" : "=v"(r) : "v"(lo), "v"(hi));
    return r;
}
// packed u16 max (valid bf16 max for non-negative values)
__device__ __forceinline__ unsigned pkmax(unsigned a, unsigned b) {
    unsigned r;
    asm("v_pk_max_u16 %0, %1, %2" : "=v"(r) : "v"(a), "v"(b));
    return r;
}
__device__ __forceinline__ uint4 pkmax4(uint4 a, uint4 b) {
    return make_uint4(pkmax(a.x, b.x), pkmax(a.y, b.y),
                      pkmax(a.z, b.z), pkmax(a.w, b.w));
}

// M=32 tile: 4 waves; wave w -> cols [w*32,(w+1)*32), 2x2 fragments.
// row = mi*16 + lhi*4 + j (mi<2), col = w*32 + ni*16 + l15 (ni<2).
struct __align__(16) FSmem {
    unsigned short h[32 * HSTR];    // 8704 B  bf16 h-tile [32][136]
    unsigned short res[32 * HSTR];  // 8704 B  residual / h1o staging tile
    float2 red[4][4][34];           // 4352 B  GN partials [w][cg][row], (sum,ss)
    float mv[32][2];                //  256 B  mean/rstd per row
};

// per-row mean/rstd over 128 cols -> s.mv  (2 shfl stages + packed LDS finish)
__device__ __forceinline__ void gn_stats(FSmem& s, const f32x4 acc[2][2],
                                         int w, int l15, int lhi, int tid)
{
    const int cg = l15 >> 2;
    #pragma unroll
    for (int mi = 0; mi < 2; ++mi) {
        #pragma unroll
        for (int j = 0; j < 4; ++j) {
            float a0 = acc[mi][0][j], a1 = acc[mi][1][j];
            float s0 = a0 + a1, s1 = a0 * a0 + a1 * a1;
            s0 += __shfl_xor(s0, 1); s1 += __shfl_xor(s1, 1);
            s0 += __shfl_xor(s0, 2); s1 += __shfl_xor(s1, 2);
            if ((l15 & 3) == 0) {
                int row = mi * 16 + lhi * 4 + j;
                s.red[w][cg][row] = make_float2(s0, s1);
            }
        }
    }
    __syncthreads();
    if (tid < 32) {
        float sm = 0.f, ss = 0.f;
        #pragma unroll
        for (int ww = 0; ww < 4; ++ww)
            #pragma unroll
            for (int cgg = 0; cgg < 4; ++cgg) {
                float2 p = s.red[ww][cgg][tid];
                sm += p.x; ss += p.y;
            }
        float mean = sm * (1.f / 128.f);
        float var = ss * (1.f / 128.f) - mean * mean;
        s.mv[tid][0] = mean;
        s.mv[tid][1] = rsqrtf(var + EPSV);
    }
    __syncthreads();
}

// acc += h_lds @ WT[kwoff..]   (A from s.h, B loaded inline)
__device__ __forceinline__ void gemm_lds(f32x4 acc[2][2], const FSmem& s,
    const unsigned short* __restrict__ WT, int K, int kwoff, int nks,
    int w, int l15, int lhi)
{
    #pragma unroll
    for (int ks = 0; ks < nks; ++ks) {
        bf16x8 af[2], bfr[2];
        #pragma unroll
        for (int mi = 0; mi < 2; ++mi)
            af[mi] = *(const bf16x8*)&s.h[(mi * 16 + l15) * HSTR + ks * 32 + lhi * 8];
        #pragma unroll
        for (int ni = 0; ni < 2; ++ni)
            bfr[ni] = *(const bf16x8*)&WT[(size_t)(w * 32 + ni * 16 + l15) * K + kwoff + ks * 32 + lhi * 8];
        #pragma unroll
        for (int mi = 0; mi < 2; ++mi)
            #pragma unroll
            for (int ni = 0; ni < 2; ++ni)
                acc[mi][ni] = __builtin_amdgcn_mfma_f32_16x16x32_bf16(
                    af[mi], bfr[ni], acc[mi][ni], 0, 0, 0);
    }
}

// acc += Xf @ WT[cols 0..128) of K=256; wave 0 stashes Xf tile -> s.res
__device__ __forceinline__ void gemm_feat_stash(f32x4 acc[2][2], FSmem& s,
    const unsigned short* __restrict__ Xf,
    const unsigned short* __restrict__ WT,
    int rowbase, int w, int l15, int lhi)
{
    #pragma unroll
    for (int ks = 0; ks < 4; ++ks) {
        bf16x8 af[2], bfr[2];
        #pragma unroll
        for (int mi = 0; mi < 2; ++mi)
            af[mi] = *(const bf16x8*)&Xf[(size_t)(rowbase + mi * 16 + l15) * 128 + ks * 32 + lhi * 8];
        if (w == 0) {
            #pragma unroll
            for (int mi = 0; mi < 2; ++mi)
                *(bf16x8*)&s.res[(mi * 16 + l15) * HSTR + ks * 32 + lhi * 8] = af[mi];
        }
        #pragma unroll
        for (int ni = 0; ni < 2; ++ni)
            bfr[ni] = *(const bf16x8*)&WT[(size_t)(w * 32 + ni * 16 + l15) * 256 + ks * 32 + lhi * 8];
        #pragma unroll
        for (int mi = 0; mi < 2; ++mi)
            #pragma unroll
            for (int ni = 0; ni < 2; ++ni)
                acc[mi][ni] = __builtin_amdgcn_mfma_f32_16x16x32_bf16(
                    af[mi], bfr[ni], acc[mi][ni], 0, 0, 0);
    }
}

// GN + relu -> s.h  (cvt_pk pairs the two ni columns)
__device__ __forceinline__ void epi_lds(const f32x4 acc[2][2], FSmem& s,
    const float* __restrict__ g, const float* __restrict__ b, int w, int l15, int lhi)
{
    float gv[2], bv[2];
    #pragma unroll
    for (int ni = 0; ni < 2; ++ni) {
        int col = w * 32 + ni * 16 + l15;
        gv[ni] = g[col]; bv[ni] = b[col];
    }
    #pragma unroll
    for (int mi = 0; mi < 2; ++mi)
        #pragma unroll
        for (int j = 0; j < 4; ++j) {
            int row = mi * 16 + lhi * 4 + j;
            float mean = s.mv[row][0], rstd = s.mv[row][1];
            float v0 = fmaxf((acc[mi][0][j] - mean) * rstd * gv[0] + bv[0], 0.f);
            float v1 = fmaxf((acc[mi][1][j] - mean) * rstd * gv[1] + bv[1], 0.f);
            unsigned pk = cvt_pk_bf16(v0, v1);
            int c0 = w * 32 + l15;
            s.h[row * HSTR + c0]      = (unsigned short)pk;
            s.h[row * HSTR + c0 + 16] = (unsigned short)(pk >> 16);
        }
}

// GN in-register (no relu)
__device__ __forceinline__ void norm_reg(f32x4 acc[2][2], const FSmem& s,
    const float* __restrict__ g, const float* __restrict__ b, int w, int l15, int lhi)
{
    float gv[2], bv[2];
    #pragma unroll
    for (int ni = 0; ni < 2; ++ni) {
        int col = w * 32 + ni * 16 + l15;
        gv[ni] = g[col]; bv[ni] = b[col];
    }
    #pragma unroll
    for (int mi = 0; mi < 2; ++mi)
        #pragma unroll
        for (int j = 0; j < 4; ++j) {
            int row = mi * 16 + lhi * 4 + j;
            float mean = s.mv[row][0], rstd = s.mv[row][1];
            #pragma unroll
            for (int ni = 0; ni < 2; ++ni)
                acc[mi][ni][j] = (acc[mi][ni][j] - mean) * rstd * gv[ni] + bv[ni];
        }
}

// vectorized tile writeout: LDS [32][HSTR] -> global row-major [rowbase..][128]
__device__ __forceinline__ void vec_out(const unsigned short* __restrict__ t,
    unsigned short* __restrict__ dst, int rowbase, int nrows, int tid)
{
    #pragma unroll
    for (int it = 0; it < 2; ++it) {
        int c = tid * 2 + it;              // 0..511
        int row = c >> 4, col8 = (c & 15) * 8;
        if (rowbase + row < nrows)
            *(bf16x8*)&dst[(size_t)(rowbase + row) * NMAP + col8] =
                *(const bf16x8*)&t[row * HSTR + col8];
    }
}

// ---------------------------------------------------------------------------
// input stage + first fc1, all fused (M=32 tile)
__global__ __launch_bounds__(256) void input_fused(
    const unsigned short* __restrict__ X32,       // [N+64][32] bf16
    const unsigned short* __restrict__ wts,
    const float* __restrict__ g1, const float* __restrict__ b1,
    const float* __restrict__ gt, const float* __restrict__ bt,
    const float* __restrict__ g2, const float* __restrict__ b2,
    const float* __restrict__ g1n, const float* __restrict__ b1n,
    unsigned short* __restrict__ fbf, unsigned short* __restrict__ h1bf,
    int nrows)
{
    __shared__ FSmem s;
    const int tid = threadIdx.x;
    const int w = tid >> 6, l = tid & 63, l15 = l & 15, lhi = l >> 4;
    const int rowbase = blockIdx.x * 32;

    const unsigned short* w1T = wts;              // K=32
    const unsigned short* wtT = wts + 4096;       // K=32
    const unsigned short* w2T = wts + 8192;       // K=128
    const unsigned short* f1T = wts + 24576;      // fc1[0], K=128

    f32x4 accA[2][2] = {}, accT[2][2] = {};
    {
        bf16x8 af[2], b1f[2], btf[2];
        #pragma unroll
        for (int mi = 0; mi < 2; ++mi)
            af[mi] = *(const bf16x8*)&X32[(size_t)(rowbase + mi * 16 + l15) * 32 + lhi * 8];
        #pragma unroll
        for (int ni = 0; ni < 2; ++ni) {
            int col = w * 32 + ni * 16 + l15;
            b1f[ni] = *(const bf16x8*)&w1T[(size_t)col * 32 + lhi * 8];
            btf[ni] = *(const bf16x8*)&wtT[(size_t)col * 32 + lhi * 8];
        }
        #pragma unroll
        for (int mi = 0; mi < 2; ++mi)
            #pragma unroll
            for (int ni = 0; ni < 2; ++ni) {
                accA[mi][ni] = __builtin_amdgcn_mfma_f32_16x16x32_bf16(af[mi], b1f[ni], accA[mi][ni], 0, 0, 0);
                accT[mi][ni] = __builtin_amdgcn_mfma_f32_16x16x32_bf16(af[mi], btf[ni], accT[mi][ni], 0, 0, 0);
            }
    }

    gn_stats(s, accT, w, l15, lhi, tid);
    norm_reg(accT, s, gt, bt, w, l15, lhi);       // T = GN(X@wt), no relu
    gn_stats(s, accA, w, l15, lhi, tid);
    epi_lds(accA, s, g1, b1, w, l15, lhi);        // h1 -> s.h
    __syncthreads();

    // stage 1: feat = relu(GN(h1@w2) + T) -> s.h only
    f32x4 accB[2][2] = {};
    gemm_lds(accB, s, w2T, 128, 0, 4, w, l15, lhi);
    gn_stats(s, accB, w, l15, lhi, tid);
    {
        float gv[2], bv[2];
        #pragma unroll
        for (int ni = 0; ni < 2; ++ni) {
            int col = w * 32 + ni * 16 + l15;
            gv[ni] = g2[col]; bv[ni] = b2[col];
        }
        #pragma unroll
        for (int mi = 0; mi < 2; ++mi)
            #pragma unroll
            for (int j = 0; j < 4; ++j) {
                int rl = mi * 16 + lhi * 4 + j;
                float mean = s.mv[rl][0], rstd = s.mv[rl][1];
                float v0 = fmaxf((accB[mi][0][j] - mean) * rstd * gv[0] + bv[0]
                                 + accT[mi][0][j], 0.f);
                float v1 = fmaxf((accB[mi][1][j] - mean) * rstd * gv[1] + bv[1]
                                 + accT[mi][1][j], 0.f);
                unsigned pk = cvt_pk_bf16(v0, v1);
                int c0 = w * 32 + l15;
                s.h[rl * HSTR + c0]      = (unsigned short)pk;
                s.h[rl * HSTR + c0 + 16] = (unsigned short)(pk >> 16);
            }
    }
    __syncthreads();

    // stage 2: h1o = relu(GN(feat@fc1_0))
    f32x4 accC[2][2] = {};
    gemm_lds(accC, s, f1T, 128, 0, 4, w, l15, lhi);
    gn_stats(s, accC, w, l15, lhi, tid);           // ends with barrier
    vec_out(s.h, fbf, rowbase, nrows, tid);        // feat writeout (s.h intact)
    {
        float gv[2], bv[2];
        #pragma unroll
        for (int ni = 0; ni < 2; ++ni) {
            int col = w * 32 + ni * 16 + l15;
            gv[ni] = g1n[col]; bv[ni] = b1n[col];
        }
        #pragma unroll
        for (int mi = 0; mi < 2; ++mi)
            #pragma unroll
            for (int j = 0; j < 4; ++j) {
                int rl = mi * 16 + lhi * 4 + j;
                float mean = s.mv[rl][0], rstd = s.mv[rl][1];
                float v0 = fmaxf((accC[mi][0][j] - mean) * rstd * gv[0] + bv[0], 0.f);
                float v1 = fmaxf((accC[mi][1][j] - mean) * rstd * gv[1] + bv[1], 0.f);
                unsigned pk = cvt_pk_bf16(v0, v1);
                int c0 = w * 32 + l15;
                s.res[rl * HSTR + c0]      = (unsigned short)pk;
                s.res[rl * HSTR + c0 + 16] = (unsigned short)(pk >> 16);
            }
    }
    __syncthreads();
    vec_out(s.res, h1bf, rowbase, nrows, tid);     // h1 writeout (row-major)
}

// ---------------------------------------------------------------------------
// one agg block WITH fused seg-max gather (stage 0), M=32 tile:
//   agg(s.h) = segmax(h1in[in-edges]); h = relu(GN([feat|agg]@fc2));
//   nf = relu(GN(h@lin)+feat); feat<-nf; h1out = relu(GN(nf@fc1_next))
// Gather: 8 lanes/node, all 32 nodes parallel, 4-edge unroll, dual acc pairs.
__global__ __launch_bounds__(256) void block_fused(
    unsigned short* __restrict__ fbf,
    const int* __restrict__ rp, const int* __restrict__ su,
    const unsigned* __restrict__ h1in,            // u32 view, 64 uints/row
    const unsigned short* __restrict__ wts, int kblk,
    const float* __restrict__ g2, const float* __restrict__ b2,
    const float* __restrict__ gl, const float* __restrict__ bl,
    const float* __restrict__ g1n, const float* __restrict__ b1n,
    unsigned short* __restrict__ h1out, float* __restrict__ outf,
    int nrows, int has_next)
{
    __shared__ FSmem s;
    const int tid = threadIdx.x;
    const int w = tid >> 6, l = tid & 63, l15 = l & 15, lhi = l >> 4;
    const int rowbase = blockIdx.x * 32;

    const unsigned short* fc2T = wts + 90112 + (size_t)kblk * 32768;   // K=256
    const unsigned short* linT = wts + 221184 + (size_t)kblk * 16384;  // K=128
    const unsigned short* f1T  = wts + 24576 + (size_t)(kblk + 1) * 16384;

    // ---- stage 0: parallel seg-max gather -> s.h (agg tile) ----
    {
        const int node8 = tid >> 3, g = tid & 7;
        const int node = rowbase + node8;
        uint4 A0 = make_uint4(0, 0, 0, 0), A1 = make_uint4(0, 0, 0, 0);
        uint4 B0 = make_uint4(0, 0, 0, 0), B1 = make_uint4(0, 0, 0, 0);
        if (node < nrows) {
            int j = rp[node], e0 = rp[node + 1];
            for (; j + 3 < e0; j += 4) {
                const uint4* r0 = (const uint4*)&h1in[(size_t)su[j] * 64 + g * 8];
                const uint4* r1 = (const uint4*)&h1in[(size_t)su[j + 1] * 64 + g * 8];
                const uint4* r2 = (const uint4*)&h1in[(size_t)su[j + 2] * 64 + g * 8];
                const uint4* r3 = (const uint4*)&h1in[(size_t)su[j + 3] * 64 + g * 8];
                uint4 x0 = r0[0], x1 = r0[1];
                uint4 y0 = r1[0], y1 = r1[1];
                uint4 z0 = r2[0], z1 = r2[1];
                uint4 q0 = r3[0], q1 = r3[1];
                A0 = pkmax4(A0, x0); A1 = pkmax4(A1, x1);
                B0 = pkmax4(B0, y0); B1 = pkmax4(B1, y1);
                A0 = pkmax4(A0, z0); A1 = pkmax4(A1, z1);
                B0 = pkmax4(B0, q0); B1 = pkmax4(B1, q1);
            }
            for (; j < e0; ++j) {
                const uint4* r0 = (const uint4*)&h1in[(size_t)su[j] * 64 + g * 8];
                A0 = pkmax4(A0, r0[0]); A1 = pkmax4(A1, r0[1]);
            }
            A0 = pkmax4(A0, B0); A1 = pkmax4(A1, B1);
        }
        *(uint4*)&s.h[node8 * HSTR + g * 16]     = A0;
        *(uint4*)&s.h[node8 * HSTR + g * 16 + 8] = A1;
    }
    __syncthreads();

    // ---- stage 1: h = relu(GN([feat|agg]@fc2)); feat tile stashed -> s.res ----
    f32x4 acc2[2][2] = {};
    gemm_feat_stash(acc2, s, fbf, fc2T, rowbase, w, l15, lhi);   // feat half
    gemm_lds(acc2, s, fc2T, 256, 128, 4, w, l15, lhi);           // agg half (LDS)
    gn_stats(s, acc2, w, l15, lhi, tid);      // barriers: s.h reads complete
    epi_lds(acc2, s, g2, b2, w, l15, lhi);    // overwrite s.h with h
    __syncthreads();

    // ---- stage 2: nf = relu(GN(h@lin) + feat)  (residual from s.res) ----
    f32x4 acc3[2][2] = {};
    gemm_lds(acc3, s, linT, 128, 0, 4, w, l15, lhi);
    gn_stats(s, acc3, w, l15, lhi, tid);
    {
        float gv[2], bv[2];
        #pragma unroll
        for (int ni = 0; ni < 2; ++ni) {
            int col = w * 32 + ni * 16 + l15;
            gv[ni] = gl[col]; bv[ni] = bl[col];
        }
        #pragma unroll
        for (int mi = 0; mi < 2; ++mi)
            #pragma unroll
            for (int j = 0; j < 4; ++j) {
                int rl = mi * 16 + lhi * 4 + j;
                int row = rowbase + rl;
                float mean = s.mv[rl][0], rstd = s.mv[rl][1];
                int c0 = w * 32 + l15;
                float v0 = (acc3[mi][0][j] - mean) * rstd * gv[0] + bv[0]
                         + bf2f(s.res[rl * HSTR + c0]);
                float v1 = (acc3[mi][1][j] - mean) * rstd * gv[1] + bv[1]
                         + bf2f(s.res[rl * HSTR + c0 + 16]);
                v0 = fmaxf(v0, 0.f); v1 = fmaxf(v1, 0.f);
                unsigned pk = cvt_pk_bf16(v0, v1);
                s.h[rl * HSTR + c0]      = (unsigned short)pk;
                s.h[rl * HSTR + c0 + 16] = (unsigned short)(pk >> 16);
                if (outf && row < nrows) {
                    outf[(size_t)row * NMAP + c0]      = v0;
                    outf[(size_t)row * NMAP + c0 + 16] = v1;
                }
            }
    }

    // ---- stage 3: h1out = relu(GN(nf@fc1_next)); vectorized writeouts ----
    if (has_next) {
        __syncthreads();
        f32x4 acc4[2][2] = {};
        gemm_lds(acc4, s, f1T, 128, 0, 4, w, l15, lhi);
        gn_stats(s, acc4, w, l15, lhi, tid);       // ends with barrier
        vec_out(s.h, fbf, rowbase, nrows, tid);    // nf -> fbf (s.h intact)
        {
            float gv[2], bv[2];
            #pragma unroll
            for (int ni = 0; ni < 2; ++ni) {
                int col = w * 32 + ni * 16 + l15;
                gv[ni] = g1n[col]; bv[ni] = b1n[col];
            }
            #pragma unroll
            for (int mi = 0; mi < 2; ++mi)
                #pragma unroll
                for (int j = 0; j < 4; ++j) {
                    int rl = mi * 16 + lhi * 4 + j;
                    float mean = s.mv[rl][0], rstd = s.mv[rl][1];
                    float v0 = fmaxf((acc4[mi][0][j] - mean) * rstd * gv[0] + bv[0], 0.f);
                    float v1 = fmaxf((acc4[mi][1][j] - mean) * rstd * gv[1] + bv[1], 0.f);
                    unsigned pk = cvt_pk_bf16(v0, v1);
                    int c0 = w * 32 + l15;
                    s.res[rl * HSTR + c0]      = (unsigned short)pk;
                    s.res[rl * HSTR + c0 + 16] = (unsigned short)(pk >> 16);
                }
        }
        __syncthreads();
        vec_out(s.res, h1out, rowbase, nrows, tid); // h1out (row-major)
    }
}

// ---------------------------------------------------------------------------
// all weight converts in one kernel.  wts layout (shorts):
//   w1T@0(4096) wtT@4096(4096) w2T@8192(16384) fc1T@24576(65536)
//   fc2T@90112(131072) linT@221184(65536)  total 286720
__global__ __launch_bounds__(256) void cvt_all_w(
    const float* __restrict__ in_w1, const float* __restrict__ in_wt,
    const float* __restrict__ in_w2, const float* __restrict__ fc1_w,
    const float* __restrict__ fc2_w, const float* __restrict__ lin_w,
    unsigned short* __restrict__ wts)
{
    int idx = blockIdx.x * 256 + threadIdx.x;
    if (idx >= 286720) return;
    const float* src; int off, K, Kreal;
    if (idx < 4096)        { src = in_w1; off = idx;          K = 32;  Kreal = 22; }
    else if (idx < 8192)   { src = in_wt; off = idx - 4096;   K = 32;  Kreal = 22; }
    else if (idx < 24576)  { src = in_w2; off = idx - 8192;   K = 128; Kreal = 128; }
    else if (idx < 90112)  { src = fc1_w; off = idx - 24576;  K = 128; Kreal = 128; }
    else if (idx < 221184) { src = fc2_w; off = idx - 90112;  K = 256; Kreal = 256; }
    else                   { src = lin_w; off = idx - 221184; K = 128; Kreal = 128; }
    int per = 128 * K;
    int m = off / per, rem = off - m * per;
    int c = rem / K, k = rem - c * K;
    float val = (k < Kreal) ? src[(size_t)m * per + (size_t)k * 128 + c] : 0.f;
    wts[idx] = f2bf(val);
}

// feats fp32 [N][22] -> bf16 [N+64][32] zero-padded
__global__ __launch_bounds__(256) void cvt_feats_kernel(
    const float* __restrict__ src, unsigned short* __restrict__ dst, int N)
{
    int idx = blockIdx.x * 256 + threadIdx.x;
    int n = idx >> 5, kk = idx & 31;
    if (n < N + 64) {
        float v = (n < N && kk < 22) ? src[(size_t)n * 22 + kk] : 0.f;
        dst[idx] = f2bf(v);
    }
}

// ---------------- CSR build: both scales fused per phase -------------------
__global__ __launch_bounds__(256) void hist2_kernel(
    const int* __restrict__ v, int* __restrict__ rp, int E, int N)
{
    int e = blockIdx.x * 256 + threadIdx.x;
    if (e < 2 * E) {
        int sc = e >= E;
        atomicAdd(&rp[sc * (N + 1) + v[e] + 1], 1);
    }
}

__global__ __launch_bounds__(256) void scan1_kernel(
    int* __restrict__ rp, int* __restrict__ part, int n1, int NB)
{
    __shared__ int wtot[4];
    const int sc = blockIdx.x / NB, chunk = blockIdx.x - sc * NB;
    int* data = rp + (size_t)sc * n1;
    const int tid = threadIdx.x;
    const int base = chunk * SCHUNK + tid * 8;
    int vv[8];
    #pragma unroll
    for (int i = 0; i < 8; ++i) {
        int idx = base + i;
        vv[i] = (idx < n1) ? data[idx] : 0;
    }
    #pragma unroll
    for (int i = 1; i < 8; ++i) vv[i] += vv[i - 1];
    int tsum = vv[7];
    const int lane = tid & 63, wid = tid >> 6;
    int scn = tsum;
    #pragma unroll
    for (int d = 1; d < 64; d <<= 1) {
        int t = __shfl_up(scn, d);
        if (lane >= d) scn += t;
    }
    if (lane == 63) wtot[wid] = scn;
    __syncthreads();
    int woff = 0;
    for (int w2 = 0; w2 < wid; ++w2) woff += wtot[w2];
    const int excl = scn - tsum + woff;
    #pragma unroll
    for (int i = 0; i < 8; ++i) {
        int idx = base + i;
        if (idx < n1) data[idx] = vv[i] + excl;
    }
    if (tid == 255) part[blockIdx.x] = excl + tsum;
}

__global__ __launch_bounds__(256) void scan2_kernel(int* part, int NB)
{
    __shared__ int wsum[4];
    int* data = part + blockIdx.x * NB;
    const int tid = threadIdx.x;
    const int lane = tid & 63, wid = tid >> 6;
    int carry = 0;
    for (int base = 0; base < NB; base += 256) {
        int i = base + tid;
        int val = (i < NB) ? data[i] : 0;
        #pragma unroll
        for (int d = 1; d < 64; d <<= 1) {
            int t = __shfl_up(val, d);
            if (lane >= d) val += t;
        }
        if (lane == 63) wsum[wid] = val;
        __syncthreads();
        int woff = 0;
        for (int w = 0; w < wid; ++w) woff += wsum[w];
        int total = wsum[0] + wsum[1] + wsum[2] + wsum[3];
        val += woff + carry;
        if (i < NB) data[i] = val;
        __syncthreads();
        carry += total;
    }
}

__global__ __launch_bounds__(256) void scan3_kernel(
    int* __restrict__ rp, const int* __restrict__ part, int n1, int NB)
{
    const int nbm1 = NB - 1;
    const int sc = blockIdx.x / nbm1, i = blockIdx.x - sc * nbm1;
    int* data = rp + (size_t)sc * n1;
    const int base = (i + 1) * SCHUNK + threadIdx.x * 8;
    const int off = part[sc * NB + i];
    #pragma unroll
    for (int q = 0; q < 8; ++q) {
        int idx = base + q;
        if (idx < n1) data[idx] += off;
    }
}

// gcur[bk] = sc*E + rp[sc][min(b*256, N)]
__global__ __launch_bounds__(256) void init_gcur(
    const int* __restrict__ rp, int* __restrict__ gcur, int E, int N, int nbk)
{
    int i = blockIdx.x * 256 + threadIdx.x;
    if (i < 2 * nbk) {
        int sc = i >= nbk;
        int b = i - sc * nbk;
        int nb0 = b << BKSH; if (nb0 > N) nb0 = N;
        gcur[i] = sc * E + rp[sc * (N + 1) + nb0];
    }
}

// pass 1: scatter packed (u | vlocal<<24) into bucket regions
__global__ __launch_bounds__(256) void bucket_scatter(
    const int* __restrict__ u, const int* __restrict__ v,
    int* __restrict__ gcur, unsigned* __restrict__ pairs, int E, int nbk)
{
    __shared__ int cnt[1024], base[1024];
    const int tid = threadIdx.x;
    const int tot = 2 * E;
    const int c0 = blockIdx.x * CH;
    const int nbk2 = 2 * nbk;
    for (int i = tid; i < nbk2; i += 256) cnt[i] = 0;
    __syncthreads();
    for (int i = 0; i < CH; i += 256) {
        int e = c0 + i + tid;
        if (e < tot) {
            int sc = e >= E;
            int vv = v[e];
            atomicAdd(&cnt[sc * nbk + (vv >> BKSH)], 1);
        }
    }
    __syncthreads();
    for (int i = tid; i < nbk2; i += 256) {
        int c = cnt[i];
        base[i] = c ? atomicAdd(&gcur[i], c) : 0;
        cnt[i] = 0;
    }
    __syncthreads();
    for (int i = 0; i < CH; i += 256) {
        int e = c0 + i + tid;
        if (e < tot) {
            int sc = e >= E;
            unsigned uu = (unsigned)u[e];
            int vv = v[e];
            int bk = sc * nbk + (vv >> BKSH);
            int off = atomicAdd(&cnt[bk], 1);
            pairs[(size_t)base[bk] + off] =
                uu | ((unsigned)(vv & ((1 << BKSH) - 1)) << 24);
        }
    }
}

// pass 2: per-bucket scatter into final CSR order (writes stay in ~10KB region)
__global__ __launch_bounds__(256) void bucket_fill(
    const unsigned* __restrict__ pairs, const int* __restrict__ rp,
    int* __restrict__ su, int E, int N, int nbk)
{
    __shared__ int curs[256];
    const int bk = blockIdx.x;
    const int sc = bk >= nbk;
    const int b = bk - sc * nbk;
    const int nb0 = b << BKSH;
    const int nb1 = min(nb0 + (1 << BKSH), N);
    const int nn = nb1 - nb0;
    const int* rps = rp + (size_t)sc * (N + 1);
    const int tid = threadIdx.x;
    const int rstart = rps[nb0], rend = rps[nb1];
    if (tid < nn) curs[tid] = rps[nb0 + tid];
    __syncthreads();
    int* sus = su + (size_t)sc * E;
    for (int idx = rstart + tid; idx < rend; idx += 256) {
        unsigned pr = pairs[(size_t)sc * E + idx];
        int vloc = (int)(pr >> 24);
        int pos = atomicAdd(&curs[vloc], 1);
        sus[pos] = (int)(pr & 0x00FFFFFFu);
    }
}

// ---------------------------------------------------------------------------
extern "C" void kernel_launch(void* const* d_in, const int* in_sizes, int n_in,
                              void* d_out, int out_size, void* d_ws, size_t ws_size,
                              hipStream_t stream)
{
    const float* feats = (const float*)d_in[0];
    const int*   u     = (const int*)d_in[1];
    const int*   v     = (const int*)d_in[2];
    const float* in_w1 = (const float*)d_in[3];
    const float* in_g1 = (const float*)d_in[4];
    const float* in_b1 = (const float*)d_in[5];
    const float* in_w2 = (const float*)d_in[6];
    const float* in_g2 = (const float*)d_in[7];
    const float* in_b2 = (const float*)d_in[8];
    const float* in_wt = (const float*)d_in[9];
    const float* in_gt = (const float*)d_in[10];
    const float* in_bt = (const float*)d_in[11];
    const float* fc1_w = (const float*)d_in[12];
    const float* fc1_g = (const float*)d_in[13];
    const float* fc1_b = (const float*)d_in[14];
    const float* fc2_w = (const float*)d_in[15];
    const float* fc2_g = (const float*)d_in[16];
    const float* fc2_b = (const float*)d_in[17];
    const float* lin_w = (const float*)d_in[18];
    const float* lin_g = (const float*)d_in[19];
    const float* lin_b = (const float*)d_in[20];

    const int N = in_sizes[0] / 22;
    const int E = in_sizes[1] / 2;
    const size_t nmp = (size_t)(N + 64) * NMAP;

    unsigned short* fbf  = (unsigned short*)d_ws;      // running feat
    unsigned short* h1A  = fbf + nmp;                  // h1 ping
    unsigned short* h1B  = h1A + nmp;                  // h1 pong / pairs scratch
    unsigned short* x32  = h1B + nmp;                  // padded input feats
    unsigned short* wts  = x32 + (size_t)(N + 64) * 32;
    unsigned short* wend = wts + 286720;

    int* rp   = (int*)wend;          // 2*(N+1)
    int* su   = rp + 2 * (N + 1);    // 2*E
    int* part = su + 2 * (size_t)E;  // scan partials (<=128)
    int* gcur = part + 256;          // 2*nbk (<=1024)
    unsigned* pairs = (unsigned*)h1B; // 8 MB; free until first block_fused stage-3

    const int nbk = (N + (1 << BKSH) - 1) >> BKSH;     // buckets per scale

    // ---- one-time converts ----
    cvt_feats_kernel<<<((N + 64) * 32 + 255) / 256, 256, 0, stream>>>(feats, x32, N);
    cvt_all_w<<<(286720 + 255) / 256, 256, 0, stream>>>(
        in_w1, in_wt, in_w2, fc1_w, fc2_w, lin_w, wts);

    // ---- one-time CSR build ----
    {
        const int n1 = N + 1;
        const int NB = (n1 + SCHUNK - 1) / SCHUNK;
        hipMemsetAsync(rp, 0, 2 * (size_t)n1 * sizeof(int), stream);
        hist2_kernel<<<(2 * E + 255) / 256, 256, 0, stream>>>(v, rp, E, N);
        scan1_kernel<<<2 * NB, 256, 0, stream>>>(rp, part, n1, NB);
        scan2_kernel<<<2, 256, 0, stream>>>(part, NB);
        scan3_kernel<<<2 * (NB - 1), 256, 0, stream>>>(rp, part, n1, NB);
        init_gcur<<<(2 * nbk + 255) / 256, 256, 0, stream>>>(rp, gcur, E, N, nbk);
        bucket_scatter<<<(2 * E + CH - 1) / CH, 256, 0, stream>>>(
            u, v, gcur, pairs, E, nbk);
        bucket_fill<<<2 * nbk, 256, 0, stream>>>(pairs, rp, su, E, N, nbk);
    }

    const int GB = (N + 31) / 32;

    // ---- input stage + fc1[0] ----
    input_fused<<<GB, 256, 0, stream>>>(x32, wts,
        in_g1, in_b1, in_gt, in_bt, in_g2, in_b2,
        fc1_g, fc1_b, fbf, h1A, N);

    // ---- agg blocks (seg_max fused; h1 ping-pongs A->B->A->B) ----
    for (int k = 0; k < 4; ++k) {
        int is = k & 1;
        int has_next = (k < 3);
        unsigned short* h1in  = (k & 1) ? h1B : h1A;
        unsigned short* h1out = (k & 1) ? h1A : h1B;
        block_fused<<<GB, 256, 0, stream>>>(fbf,
            rp + (size_t)is * (N + 1), su + (size_t)is * E,
            (const unsigned*)h1in, wts, k,
            fc2_g + k * 128, fc2_b + k * 128,
            lin_g + k * 128, lin_b + k * 128,
            has_next ? fc1_g + (k + 1) * 128 : nullptr,
            has_next ? fc1_b + (k + 1) * 128 : nullptr,
            h1out, (k == 3) ? (float*)d_out : nullptr, N, has_next);
    }
}

// Round 17
// 524.179 us; speedup vs baseline: 1.5583x; 1.1488x over previous
//
#include <hip/hip_runtime.h>

#define NMAP 128
#define EPSV 1e-5f
#define HSTR 136        // LDS h-tile row stride in shorts (272 B)
#define BKSH 8          // 256 nodes per bucket
#define CH 8192         // edges per bucket kernel workgroup

typedef __attribute__((ext_vector_type(8))) short bf16x8;   // 8 bf16 = 4 VGPRs
typedef __attribute__((ext_vector_type(4))) float f32x4;

__device__ __forceinline__ unsigned short f2bf(float f) {
    union { float f; unsigned u; } x; x.f = f;
    unsigned u = x.u;
    return (unsigned short)((u + 0x7fffu + ((u >> 16) & 1u)) >> 16);  // RNE
}
__device__ __forceinline__ float bf2f(unsigned short h) {
    union { unsigned u; float f; } x; x.u = ((unsigned)h) << 16;
    return x.f;
}
// two f32 -> packed bf16 pair (RNE, same rounding as f2bf), 1 VALU op
__device__ __forceinline__ unsigned cvt_pk_bf16(float lo, float hi) {
    unsigned r;
    asm("v_cvt_pk_bf16_f32 %0, %1, %2" : "=v"(r) : "v"(lo), "v"(hi));
    return r;
}
// packed u16 max (valid bf16 max for non-negative values)
__device__ __forceinline__ unsigned pkmax(unsigned a, unsigned b) {
    unsigned r;
    asm("v_pk_max_u16 %0, %1, %2" : "=v"(r) : "v"(a), "v"(b));
    return r;
}
__device__ __forceinline__ uint4 pkmax4(uint4 a, uint4 b) {
    return make_uint4(pkmax(a.x, b.x), pkmax(a.y, b.y),
                      pkmax(a.z, b.z), pkmax(a.w, b.w));
}

// M=32 tile: 4 waves; wave w -> cols [w*32,(w+1)*32), 2x2 fragments.
// row = mi*16 + lhi*4 + j (mi<2), col = w*32 + ni*16 + l15 (ni<2).
struct __align__(16) FSmem {
    unsigned short h[32 * HSTR];    // 8704 B  bf16 h-tile [32][136]
    unsigned short res[32 * HSTR];  // 8704 B  residual / h1o staging tile
    float2 red[4][4][34];           // 4352 B  GN partials [w][cg][row], (sum,ss)
    float mv[32][2];                //  256 B  mean/rstd per row
};

// per-row mean/rstd over 128 cols -> s.mv  (2 shfl stages + packed LDS finish)
__device__ __forceinline__ void gn_stats(FSmem& s, const f32x4 acc[2][2],
                                         int w, int l15, int lhi, int tid)
{
    const int cg = l15 >> 2;
    #pragma unroll
    for (int mi = 0; mi < 2; ++mi) {
        #pragma unroll
        for (int j = 0; j < 4; ++j) {
            float a0 = acc[mi][0][j], a1 = acc[mi][1][j];
            float s0 = a0 + a1, s1 = a0 * a0 + a1 * a1;
            s0 += __shfl_xor(s0, 1); s1 += __shfl_xor(s1, 1);
            s0 += __shfl_xor(s0, 2); s1 += __shfl_xor(s1, 2);
            if ((l15 & 3) == 0) {
                int row = mi * 16 + lhi * 4 + j;
                s.red[w][cg][row] = make_float2(s0, s1);
            }
        }
    }
    __syncthreads();
    if (tid < 32) {
        float sm = 0.f, ss = 0.f;
        #pragma unroll
        for (int ww = 0; ww < 4; ++ww)
            #pragma unroll
            for (int cgg = 0; cgg < 4; ++cgg) {
                float2 p = s.red[ww][cgg][tid];
                sm += p.x; ss += p.y;
            }
        float mean = sm * (1.f / 128.f);
        float var = ss * (1.f / 128.f) - mean * mean;
        s.mv[tid][0] = mean;
        s.mv[tid][1] = rsqrtf(var + EPSV);
    }
    __syncthreads();
}

// acc += h_lds @ WT[kwoff..]   (A from s.h, B loaded inline)
__device__ __forceinline__ void gemm_lds(f32x4 acc[2][2], const FSmem& s,
    const unsigned short* __restrict__ WT, int K, int kwoff, int nks,
    int w, int l15, int lhi)
{
    #pragma unroll
    for (int ks = 0; ks < nks; ++ks) {
        bf16x8 af[2], bfr[2];
        #pragma unroll
        for (int mi = 0; mi < 2; ++mi)
            af[mi] = *(const bf16x8*)&s.h[(mi * 16 + l15) * HSTR + ks * 32 + lhi * 8];
        #pragma unroll
        for (int ni = 0; ni < 2; ++ni)
            bfr[ni] = *(const bf16x8*)&WT[(size_t)(w * 32 + ni * 16 + l15) * K + kwoff + ks * 32 + lhi * 8];
        #pragma unroll
        for (int mi = 0; mi < 2; ++mi)
            #pragma unroll
            for (int ni = 0; ni < 2; ++ni)
                acc[mi][ni] = __builtin_amdgcn_mfma_f32_16x16x32_bf16(
                    af[mi], bfr[ni], acc[mi][ni], 0, 0, 0);
    }
}

// acc += Xf @ WT[cols 0..128) of K=256; wave 0 stashes Xf tile -> s.res
__device__ __forceinline__ void gemm_feat_stash(f32x4 acc[2][2], FSmem& s,
    const unsigned short* __restrict__ Xf,
    const unsigned short* __restrict__ WT,
    int rowbase, int w, int l15, int lhi)
{
    #pragma unroll
    for (int ks = 0; ks < 4; ++ks) {
        bf16x8 af[2], bfr[2];
        #pragma unroll
        for (int mi = 0; mi < 2; ++mi)
            af[mi] = *(const bf16x8*)&Xf[(size_t)(rowbase + mi * 16 + l15) * 128 + ks * 32 + lhi * 8];
        if (w == 0) {
            #pragma unroll
            for (int mi = 0; mi < 2; ++mi)
                *(bf16x8*)&s.res[(mi * 16 + l15) * HSTR + ks * 32 + lhi * 8] = af[mi];
        }
        #pragma unroll
        for (int ni = 0; ni < 2; ++ni)
            bfr[ni] = *(const bf16x8*)&WT[(size_t)(w * 32 + ni * 16 + l15) * 256 + ks * 32 + lhi * 8];
        #pragma unroll
        for (int mi = 0; mi < 2; ++mi)
            #pragma unroll
            for (int ni = 0; ni < 2; ++ni)
                acc[mi][ni] = __builtin_amdgcn_mfma_f32_16x16x32_bf16(
                    af[mi], bfr[ni], acc[mi][ni], 0, 0, 0);
    }
}

// GN + relu -> s.h  (cvt_pk pairs the two ni columns)
__device__ __forceinline__ void epi_lds(const f32x4 acc[2][2], FSmem& s,
    const float* __restrict__ g, const float* __restrict__ b, int w, int l15, int lhi)
{
    float gv[2], bv[2];
    #pragma unroll
    for (int ni = 0; ni < 2; ++ni) {
        int col = w * 32 + ni * 16 + l15;
        gv[ni] = g[col]; bv[ni] = b[col];
    }
    #pragma unroll
    for (int mi = 0; mi < 2; ++mi)
        #pragma unroll
        for (int j = 0; j < 4; ++j) {
            int row = mi * 16 + lhi * 4 + j;
            float mean = s.mv[row][0], rstd = s.mv[row][1];
            float v0 = fmaxf((acc[mi][0][j] - mean) * rstd * gv[0] + bv[0], 0.f);
            float v1 = fmaxf((acc[mi][1][j] - mean) * rstd * gv[1] + bv[1], 0.f);
            unsigned pk = cvt_pk_bf16(v0, v1);
            int c0 = w * 32 + l15;
            s.h[row * HSTR + c0]      = (unsigned short)pk;
            s.h[row * HSTR + c0 + 16] = (unsigned short)(pk >> 16);
        }
}

// GN in-register (no relu)
__device__ __forceinline__ void norm_reg(f32x4 acc[2][2], const FSmem& s,
    const float* __restrict__ g, const float* __restrict__ b, int w, int l15, int lhi)
{
    float gv[2], bv[2];
    #pragma unroll
    for (int ni = 0; ni < 2; ++ni) {
        int col = w * 32 + ni * 16 + l15;
        gv[ni] = g[col]; bv[ni] = b[col];
    }
    #pragma unroll
    for (int mi = 0; mi < 2; ++mi)
        #pragma unroll
        for (int j = 0; j < 4; ++j) {
            int row = mi * 16 + lhi * 4 + j;
            float mean = s.mv[row][0], rstd = s.mv[row][1];
            #pragma unroll
            for (int ni = 0; ni < 2; ++ni)
                acc[mi][ni][j] = (acc[mi][ni][j] - mean) * rstd * gv[ni] + bv[ni];
        }
}

// vectorized tile writeout: LDS [32][HSTR] -> global row-major [rowbase..][128]
__device__ __forceinline__ void vec_out(const unsigned short* __restrict__ t,
    unsigned short* __restrict__ dst, int rowbase, int nrows, int tid)
{
    #pragma unroll
    for (int it = 0; it < 2; ++it) {
        int c = tid * 2 + it;              // 0..511
        int row = c >> 4, col8 = (c & 15) * 8;
        if (rowbase + row < nrows)
            *(bf16x8*)&dst[(size_t)(rowbase + row) * NMAP + col8] =
                *(const bf16x8*)&t[row * HSTR + col8];
    }
}

// ---------------------------------------------------------------------------
// input stage + first fc1, all fused (M=32 tile)
__global__ __launch_bounds__(256) void input_fused(
    const unsigned short* __restrict__ X32,       // [N+64][32] bf16
    const unsigned short* __restrict__ wts,
    const float* __restrict__ g1, const float* __restrict__ b1,
    const float* __restrict__ gt, const float* __restrict__ bt,
    const float* __restrict__ g2, const float* __restrict__ b2,
    const float* __restrict__ g1n, const float* __restrict__ b1n,
    unsigned short* __restrict__ fbf, unsigned short* __restrict__ h1bf,
    int nrows)
{
    __shared__ FSmem s;
    const int tid = threadIdx.x;
    const int w = tid >> 6, l = tid & 63, l15 = l & 15, lhi = l >> 4;
    const int rowbase = blockIdx.x * 32;

    const unsigned short* w1T = wts;              // K=32
    const unsigned short* wtT = wts + 4096;       // K=32
    const unsigned short* w2T = wts + 8192;       // K=128
    const unsigned short* f1T = wts + 24576;      // fc1[0], K=128

    f32x4 accA[2][2] = {}, accT[2][2] = {};
    {
        bf16x8 af[2], b1f[2], btf[2];
        #pragma unroll
        for (int mi = 0; mi < 2; ++mi)
            af[mi] = *(const bf16x8*)&X32[(size_t)(rowbase + mi * 16 + l15) * 32 + lhi * 8];
        #pragma unroll
        for (int ni = 0; ni < 2; ++ni) {
            int col = w * 32 + ni * 16 + l15;
            b1f[ni] = *(const bf16x8*)&w1T[(size_t)col * 32 + lhi * 8];
            btf[ni] = *(const bf16x8*)&wtT[(size_t)col * 32 + lhi * 8];
        }
        #pragma unroll
        for (int mi = 0; mi < 2; ++mi)
            #pragma unroll
            for (int ni = 0; ni < 2; ++ni) {
                accA[mi][ni] = __builtin_amdgcn_mfma_f32_16x16x32_bf16(af[mi], b1f[ni], accA[mi][ni], 0, 0, 0);
                accT[mi][ni] = __builtin_amdgcn_mfma_f32_16x16x32_bf16(af[mi], btf[ni], accT[mi][ni], 0, 0, 0);
            }
    }

    gn_stats(s, accT, w, l15, lhi, tid);
    norm_reg(accT, s, gt, bt, w, l15, lhi);       // T = GN(X@wt), no relu
    gn_stats(s, accA, w, l15, lhi, tid);
    epi_lds(accA, s, g1, b1, w, l15, lhi);        // h1 -> s.h
    __syncthreads();

    // stage 1: feat = relu(GN(h1@w2) + T) -> s.h only
    f32x4 accB[2][2] = {};
    gemm_lds(accB, s, w2T, 128, 0, 4, w, l15, lhi);
    gn_stats(s, accB, w, l15, lhi, tid);
    {
        float gv[2], bv[2];
        #pragma unroll
        for (int ni = 0; ni < 2; ++ni) {
            int col = w * 32 + ni * 16 + l15;
            gv[ni] = g2[col]; bv[ni] = b2[col];
        }
        #pragma unroll
        for (int mi = 0; mi < 2; ++mi)
            #pragma unroll
            for (int j = 0; j < 4; ++j) {
                int rl = mi * 16 + lhi * 4 + j;
                float mean = s.mv[rl][0], rstd = s.mv[rl][1];
                float v0 = fmaxf((accB[mi][0][j] - mean) * rstd * gv[0] + bv[0]
                                 + accT[mi][0][j], 0.f);
                float v1 = fmaxf((accB[mi][1][j] - mean) * rstd * gv[1] + bv[1]
                                 + accT[mi][1][j], 0.f);
                unsigned pk = cvt_pk_bf16(v0, v1);
                int c0 = w * 32 + l15;
                s.h[rl * HSTR + c0]      = (unsigned short)pk;
                s.h[rl * HSTR + c0 + 16] = (unsigned short)(pk >> 16);
            }
    }
    __syncthreads();

    // stage 2: h1o = relu(GN(feat@fc1_0))
    f32x4 accC[2][2] = {};
    gemm_lds(accC, s, f1T, 128, 0, 4, w, l15, lhi);
    gn_stats(s, accC, w, l15, lhi, tid);           // ends with barrier
    vec_out(s.h, fbf, rowbase, nrows, tid);        // feat writeout (s.h intact)
    {
        float gv[2], bv[2];
        #pragma unroll
        for (int ni = 0; ni < 2; ++ni) {
            int col = w * 32 + ni * 16 + l15;
            gv[ni] = g1n[col]; bv[ni] = b1n[col];
        }
        #pragma unroll
        for (int mi = 0; mi < 2; ++mi)
            #pragma unroll
            for (int j = 0; j < 4; ++j) {
                int rl = mi * 16 + lhi * 4 + j;
                float mean = s.mv[rl][0], rstd = s.mv[rl][1];
                float v0 = fmaxf((accC[mi][0][j] - mean) * rstd * gv[0] + bv[0], 0.f);
                float v1 = fmaxf((accC[mi][1][j] - mean) * rstd * gv[1] + bv[1], 0.f);
                unsigned pk = cvt_pk_bf16(v0, v1);
                int c0 = w * 32 + l15;
                s.res[rl * HSTR + c0]      = (unsigned short)pk;
                s.res[rl * HSTR + c0 + 16] = (unsigned short)(pk >> 16);
            }
    }
    __syncthreads();
    vec_out(s.res, h1bf, rowbase, nrows, tid);     // h1 writeout (row-major)
}

// ---------------------------------------------------------------------------
// one agg block WITH fused seg-max gather (stage 0), M=32 tile:
//   agg(s.h) = segmax(h1in[in-edges]); h = relu(GN([feat|agg]@fc2));
//   nf = relu(GN(h@lin)+feat); feat<-nf; h1out = relu(GN(nf@fc1_next))
// Gather: 8 lanes/node, all 32 nodes parallel, 4-edge unroll, dual acc pairs.
__global__ __launch_bounds__(256) void block_fused(
    unsigned short* __restrict__ fbf,
    const int* __restrict__ rp, const int* __restrict__ su,
    const unsigned* __restrict__ h1in,            // u32 view, 64 uints/row
    const unsigned short* __restrict__ wts, int kblk,
    const float* __restrict__ g2, const float* __restrict__ b2,
    const float* __restrict__ gl, const float* __restrict__ bl,
    const float* __restrict__ g1n, const float* __restrict__ b1n,
    unsigned short* __restrict__ h1out, float* __restrict__ outf,
    int nrows, int has_next)
{
    __shared__ FSmem s;
    const int tid = threadIdx.x;
    const int w = tid >> 6, l = tid & 63, l15 = l & 15, lhi = l >> 4;
    const int rowbase = blockIdx.x * 32;

    const unsigned short* fc2T = wts + 90112 + (size_t)kblk * 32768;   // K=256
    const unsigned short* linT = wts + 221184 + (size_t)kblk * 16384;  // K=128
    const unsigned short* f1T  = wts + 24576 + (size_t)(kblk + 1) * 16384;

    // ---- stage 0: parallel seg-max gather -> s.h (agg tile) ----
    {
        const int node8 = tid >> 3, g = tid & 7;
        const int node = rowbase + node8;
        uint4 A0 = make_uint4(0, 0, 0, 0), A1 = make_uint4(0, 0, 0, 0);
        uint4 B0 = make_uint4(0, 0, 0, 0), B1 = make_uint4(0, 0, 0, 0);
        if (node < nrows) {
            int j = rp[node], e0 = rp[node + 1];
            for (; j + 3 < e0; j += 4) {
                const uint4* r0 = (const uint4*)&h1in[(size_t)su[j] * 64 + g * 8];
                const uint4* r1 = (const uint4*)&h1in[(size_t)su[j + 1] * 64 + g * 8];
                const uint4* r2 = (const uint4*)&h1in[(size_t)su[j + 2] * 64 + g * 8];
                const uint4* r3 = (const uint4*)&h1in[(size_t)su[j + 3] * 64 + g * 8];
                uint4 x0 = r0[0], x1 = r0[1];
                uint4 y0 = r1[0], y1 = r1[1];
                uint4 z0 = r2[0], z1 = r2[1];
                uint4 q0 = r3[0], q1 = r3[1];
                A0 = pkmax4(A0, x0); A1 = pkmax4(A1, x1);
                B0 = pkmax4(B0, y0); B1 = pkmax4(B1, y1);
                A0 = pkmax4(A0, z0); A1 = pkmax4(A1, z1);
                B0 = pkmax4(B0, q0); B1 = pkmax4(B1, q1);
            }
            for (; j < e0; ++j) {
                const uint4* r0 = (const uint4*)&h1in[(size_t)su[j] * 64 + g * 8];
                A0 = pkmax4(A0, r0[0]); A1 = pkmax4(A1, r0[1]);
            }
            A0 = pkmax4(A0, B0); A1 = pkmax4(A1, B1);
        }
        *(uint4*)&s.h[node8 * HSTR + g * 16]     = A0;
        *(uint4*)&s.h[node8 * HSTR + g * 16 + 8] = A1;
    }
    __syncthreads();

    // ---- stage 1: h = relu(GN([feat|agg]@fc2)); feat tile stashed -> s.res ----
    f32x4 acc2[2][2] = {};
    gemm_feat_stash(acc2, s, fbf, fc2T, rowbase, w, l15, lhi);   // feat half
    gemm_lds(acc2, s, fc2T, 256, 128, 4, w, l15, lhi);           // agg half (LDS)
    gn_stats(s, acc2, w, l15, lhi, tid);      // barriers: s.h reads complete
    epi_lds(acc2, s, g2, b2, w, l15, lhi);    // overwrite s.h with h
    __syncthreads();

    // ---- stage 2: nf = relu(GN(h@lin) + feat)  (residual from s.res) ----
    f32x4 acc3[2][2] = {};
    gemm_lds(acc3, s, linT, 128, 0, 4, w, l15, lhi);
    gn_stats(s, acc3, w, l15, lhi, tid);
    {
        float gv[2], bv[2];
        #pragma unroll
        for (int ni = 0; ni < 2; ++ni) {
            int col = w * 32 + ni * 16 + l15;
            gv[ni] = gl[col]; bv[ni] = bl[col];
        }
        #pragma unroll
        for (int mi = 0; mi < 2; ++mi)
            #pragma unroll
            for (int j = 0; j < 4; ++j) {
                int rl = mi * 16 + lhi * 4 + j;
                int row = rowbase + rl;
                float mean = s.mv[rl][0], rstd = s.mv[rl][1];
                int c0 = w * 32 + l15;
                float v0 = (acc3[mi][0][j] - mean) * rstd * gv[0] + bv[0]
                         + bf2f(s.res[rl * HSTR + c0]);
                float v1 = (acc3[mi][1][j] - mean) * rstd * gv[1] + bv[1]
                         + bf2f(s.res[rl * HSTR + c0 + 16]);
                v0 = fmaxf(v0, 0.f); v1 = fmaxf(v1, 0.f);
                unsigned pk = cvt_pk_bf16(v0, v1);
                s.h[rl * HSTR + c0]      = (unsigned short)pk;
                s.h[rl * HSTR + c0 + 16] = (unsigned short)(pk >> 16);
                if (outf && row < nrows) {
                    outf[(size_t)row * NMAP + c0]      = v0;
                    outf[(size_t)row * NMAP + c0 + 16] = v1;
                }
            }
    }

    // ---- stage 3: h1out = relu(GN(nf@fc1_next)); vectorized writeouts ----
    if (has_next) {
        __syncthreads();
        f32x4 acc4[2][2] = {};
        gemm_lds(acc4, s, f1T, 128, 0, 4, w, l15, lhi);
        gn_stats(s, acc4, w, l15, lhi, tid);       // ends with barrier
        vec_out(s.h, fbf, rowbase, nrows, tid);    // nf -> fbf (s.h intact)
        {
            float gv[2], bv[2];
            #pragma unroll
            for (int ni = 0; ni < 2; ++ni) {
                int col = w * 32 + ni * 16 + l15;
                gv[ni] = g1n[col]; bv[ni] = b1n[col];
            }
            #pragma unroll
            for (int mi = 0; mi < 2; ++mi)
                #pragma unroll
                for (int j = 0; j < 4; ++j) {
                    int rl = mi * 16 + lhi * 4 + j;
                    float mean = s.mv[rl][0], rstd = s.mv[rl][1];
                    float v0 = fmaxf((acc4[mi][0][j] - mean) * rstd * gv[0] + bv[0], 0.f);
                    float v1 = fmaxf((acc4[mi][1][j] - mean) * rstd * gv[1] + bv[1], 0.f);
                    unsigned pk = cvt_pk_bf16(v0, v1);
                    int c0 = w * 32 + l15;
                    s.res[rl * HSTR + c0]      = (unsigned short)pk;
                    s.res[rl * HSTR + c0 + 16] = (unsigned short)(pk >> 16);
                }
        }
        __syncthreads();
        vec_out(s.res, h1out, rowbase, nrows, tid); // h1out (row-major)
    }
}

// ---------------------------------------------------------------------------
// all weight converts in one kernel.  wts layout (shorts):
//   w1T@0(4096) wtT@4096(4096) w2T@8192(16384) fc1T@24576(65536)
//   fc2T@90112(131072) linT@221184(65536)  total 286720
__global__ __launch_bounds__(256) void cvt_all_w(
    const float* __restrict__ in_w1, const float* __restrict__ in_wt,
    const float* __restrict__ in_w2, const float* __restrict__ fc1_w,
    const float* __restrict__ fc2_w, const float* __restrict__ lin_w,
    unsigned short* __restrict__ wts)
{
    int idx = blockIdx.x * 256 + threadIdx.x;
    if (idx >= 286720) return;
    const float* src; int off, K, Kreal;
    if (idx < 4096)        { src = in_w1; off = idx;          K = 32;  Kreal = 22; }
    else if (idx < 8192)   { src = in_wt; off = idx - 4096;   K = 32;  Kreal = 22; }
    else if (idx < 24576)  { src = in_w2; off = idx - 8192;   K = 128; Kreal = 128; }
    else if (idx < 90112)  { src = fc1_w; off = idx - 24576;  K = 128; Kreal = 128; }
    else if (idx < 221184) { src = fc2_w; off = idx - 90112;  K = 256; Kreal = 256; }
    else                   { src = lin_w; off = idx - 221184; K = 128; Kreal = 128; }
    int per = 128 * K;
    int m = off / per, rem = off - m * per;
    int c = rem / K, k = rem - c * K;
    float val = (k < Kreal) ? src[(size_t)m * per + (size_t)k * 128 + c] : 0.f;
    wts[idx] = f2bf(val);
}

// feats fp32 [N][22] -> bf16 [N+64][32] zero-padded
__global__ __launch_bounds__(256) void cvt_feats_kernel(
    const float* __restrict__ src, unsigned short* __restrict__ dst, int N)
{
    int idx = blockIdx.x * 256 + threadIdx.x;
    int n = idx >> 5, kk = idx & 31;
    if (n < N + 64) {
        float v = (n < N && kk < 22) ? src[(size_t)n * 22 + kk] : 0.f;
        dst[idx] = f2bf(v);
    }
}

// ---------------- CSR build (bucket-granular, no global hist/scan) ---------

// count edges per bucket -> gcnt[2*nbk]
__global__ __launch_bounds__(256) void bucket_cnt(
    const int* __restrict__ v, int* __restrict__ gcnt, int E, int nbk)
{
    __shared__ int cnt[1024];
    const int tid = threadIdx.x;
    const int tot = 2 * E;
    const int c0 = blockIdx.x * CH;
    const int nbk2 = 2 * nbk;
    for (int i = tid; i < nbk2; i += 256) cnt[i] = 0;
    __syncthreads();
    for (int i = 0; i < CH; i += 256) {
        int e = c0 + i + tid;
        if (e < tot) {
            int sc = e >= E;
            atomicAdd(&cnt[sc * nbk + (v[e] >> BKSH)], 1);
        }
    }
    __syncthreads();
    for (int i = tid; i < nbk2; i += 256)
        if (cnt[i]) atomicAdd(&gcnt[i], cnt[i]);
}

// single-block exclusive scan of gcnt[0..n) -> gbase and gcur
__global__ __launch_bounds__(256) void scan_buckets(
    const int* __restrict__ gcnt, int* __restrict__ gbase,
    int* __restrict__ gcur, int n)
{
    __shared__ int wsum[4];
    const int tid = threadIdx.x;
    const int lane = tid & 63, wid = tid >> 6;
    int carry = 0;
    for (int base = 0; base < n; base += 256) {
        int i = base + tid;
        int val = (i < n) ? gcnt[i] : 0;
        int inc = val;
        #pragma unroll
        for (int d = 1; d < 64; d <<= 1) {
            int t = __shfl_up(inc, d);
            if (lane >= d) inc += t;
        }
        if (lane == 63) wsum[wid] = inc;
        __syncthreads();
        int woff = 0;
        for (int w = 0; w < wid; ++w) woff += wsum[w];
        int total = wsum[0] + wsum[1] + wsum[2] + wsum[3];
        int excl = inc - val + woff + carry;
        if (i < n) { gbase[i] = excl; gcur[i] = excl; }
        __syncthreads();
        carry += total;
    }
}

// pass 1: scatter packed (u | vlocal<<24) into bucket regions
__global__ __launch_bounds__(256) void bucket_scatter(
    const int* __restrict__ u, const int* __restrict__ v,
    int* __restrict__ gcur, unsigned* __restrict__ pairs, int E, int nbk)
{
    __shared__ int cnt[1024], base[1024];
    const int tid = threadIdx.x;
    const int tot = 2 * E;
    const int c0 = blockIdx.x * CH;
    const int nbk2 = 2 * nbk;
    for (int i = tid; i < nbk2; i += 256) cnt[i] = 0;
    __syncthreads();
    for (int i = 0; i < CH; i += 256) {
        int e = c0 + i + tid;
        if (e < tot) {
            int sc = e >= E;
            int vv = v[e];
            atomicAdd(&cnt[sc * nbk + (vv >> BKSH)], 1);
        }
    }
    __syncthreads();
    for (int i = tid; i < nbk2; i += 256) {
        int c = cnt[i];
        base[i] = c ? atomicAdd(&gcur[i], c) : 0;
        cnt[i] = 0;
    }
    __syncthreads();
    for (int i = 0; i < CH; i += 256) {
        int e = c0 + i + tid;
        if (e < tot) {
            int sc = e >= E;
            unsigned uu = (unsigned)u[e];
            int vv = v[e];
            int bk = sc * nbk + (vv >> BKSH);
            int off = atomicAdd(&cnt[bk], 1);
            pairs[(size_t)base[bk] + off] =
                uu | ((unsigned)(vv & ((1 << BKSH) - 1)) << 24);
        }
    }
}

// pass 2: per-bucket: node counts -> local scan -> write rp -> scatter su
__global__ __launch_bounds__(256) void bucket_fill2(
    const unsigned* __restrict__ pairs, const int* __restrict__ gbase,
    const int* __restrict__ gcnt, int* __restrict__ su, int* __restrict__ rp,
    int E, int N, int nbk)
{
    __shared__ int ncnt[256];
    __shared__ int wtot[4];
    const int bk = blockIdx.x;
    const int sc = bk >= nbk;
    const int b = bk - sc * nbk;
    const int nb0 = b << BKSH;
    const int nb1 = min(nb0 + (1 << BKSH), N);
    const int nn = nb1 - nb0;
    const int tid = threadIdx.x;
    const int start = gbase[bk];          // global (cross-scale) offset
    const int cntb = gcnt[bk];
    const int lbase = start - sc * E;     // within-scale offset
    ncnt[tid] = 0;
    __syncthreads();
    for (int idx = start + tid; idx < start + cntb; idx += 256)
        atomicAdd(&ncnt[pairs[idx] >> 24], 1);
    __syncthreads();
    // exclusive scan of ncnt[0..256)
    int val = ncnt[tid];
    int inc = val;
    const int lane = tid & 63, wid = tid >> 6;
    #pragma unroll
    for (int d = 1; d < 64; d <<= 1) {
        int t = __shfl_up(inc, d);
        if (lane >= d) inc += t;
    }
    if (lane == 63) wtot[wid] = inc;
    __syncthreads();
    int woff = 0;
    for (int w2 = 0; w2 < wid; ++w2) woff += wtot[w2];
    int excl = inc - val + woff;
    int* rps = rp + (size_t)sc * (N + 1);
    if (tid < nn) rps[nb0 + tid] = lbase + excl;
    if (b == nbk - 1 && tid == 0) rps[N] = E;
    __syncthreads();
    ncnt[tid] = lbase + excl;             // becomes the scatter cursor
    __syncthreads();
    int* sus = su + (size_t)sc * E;
    for (int idx = start + tid; idx < start + cntb; idx += 256) {
        unsigned pr = pairs[idx];
        int pos = atomicAdd(&ncnt[pr >> 24], 1);
        sus[pos] = (int)(pr & 0x00FFFFFFu);
    }
}

// ---------------------------------------------------------------------------
extern "C" void kernel_launch(void* const* d_in, const int* in_sizes, int n_in,
                              void* d_out, int out_size, void* d_ws, size_t ws_size,
                              hipStream_t stream)
{
    const float* feats = (const float*)d_in[0];
    const int*   u     = (const int*)d_in[1];
    const int*   v     = (const int*)d_in[2];
    const float* in_w1 = (const float*)d_in[3];
    const float* in_g1 = (const float*)d_in[4];
    const float* in_b1 = (const float*)d_in[5];
    const float* in_w2 = (const float*)d_in[6];
    const float* in_g2 = (const float*)d_in[7];
    const float* in_b2 = (const float*)d_in[8];
    const float* in_wt = (const float*)d_in[9];
    const float* in_gt = (const float*)d_in[10];
    const float* in_bt = (const float*)d_in[11];
    const float* fc1_w = (const float*)d_in[12];
    const float* fc1_g = (const float*)d_in[13];
    const float* fc1_b = (const float*)d_in[14];
    const float* fc2_w = (const float*)d_in[15];
    const float* fc2_g = (const float*)d_in[16];
    const float* fc2_b = (const float*)d_in[17];
    const float* lin_w = (const float*)d_in[18];
    const float* lin_g = (const float*)d_in[19];
    const float* lin_b = (const float*)d_in[20];

    const int N = in_sizes[0] / 22;
    const int E = in_sizes[1] / 2;
    const size_t nmp = (size_t)(N + 64) * NMAP;

    unsigned short* fbf  = (unsigned short*)d_ws;      // running feat
    unsigned short* h1A  = fbf + nmp;                  // h1 ping
    unsigned short* h1B  = h1A + nmp;                  // h1 pong / pairs scratch
    unsigned short* x32  = h1B + nmp;                  // padded input feats
    unsigned short* wts  = x32 + (size_t)(N + 64) * 32;
    unsigned short* wend = wts + 286720;

    int* rp    = (int*)wend;          // 2*(N+1)
    int* su    = rp + 2 * (N + 1);    // 2*E
    int* gcnt  = su + 2 * (size_t)E;  // 2*nbk
    int* gbase = gcnt + 1024;         // 2*nbk
    int* gcur  = gbase + 1024;        // 2*nbk
    unsigned* pairs = (unsigned*)h1B; // 8 MB; free until first block_fused stage-3

    const int nbk = (N + (1 << BKSH) - 1) >> BKSH;     // buckets per scale

    // ---- one-time converts ----
    cvt_feats_kernel<<<((N + 64) * 32 + 255) / 256, 256, 0, stream>>>(feats, x32, N);
    cvt_all_w<<<(286720 + 255) / 256, 256, 0, stream>>>(
        in_w1, in_wt, in_w2, fc1_w, fc2_w, lin_w, wts);

    // ---- one-time CSR build (bucket-granular) ----
    {
        hipMemsetAsync(gcnt, 0, 2 * (size_t)nbk * sizeof(int), stream);
        bucket_cnt<<<(2 * E + CH - 1) / CH, 256, 0, stream>>>(v, gcnt, E, nbk);
        scan_buckets<<<1, 256, 0, stream>>>(gcnt, gbase, gcur, 2 * nbk);
        bucket_scatter<<<(2 * E + CH - 1) / CH, 256, 0, stream>>>(
            u, v, gcur, pairs, E, nbk);
        bucket_fill2<<<2 * nbk, 256, 0, stream>>>(pairs, gbase, gcnt, su, rp, E, N, nbk);
    }

    const int GB = (N + 31) / 32;

    // ---- input stage + fc1[0] ----
    input_fused<<<GB, 256, 0, stream>>>(x32, wts,
        in_g1, in_b1, in_gt, in_bt, in_g2, in_b2,
        fc1_g, fc1_b, fbf, h1A, N);

    // ---- agg blocks (seg_max fused; h1 ping-pongs A->B->A->B) ----
    for (int k = 0; k < 4; ++k) {
        int is = k & 1;
        int has_next = (k < 3);
        unsigned short* h1in  = (k & 1) ? h1B : h1A;
        unsigned short* h1out = (k & 1) ? h1A : h1B;
        block_fused<<<GB, 256, 0, stream>>>(fbf,
            rp + (size_t)is * (N + 1), su + (size_t)is * E,
            (const unsigned*)h1in, wts, k,
            fc2_g + k * 128, fc2_b + k * 128,
            lin_g + k * 128, lin_b + k * 128,
            has_next ? fc1_g + (k + 1) * 128 : nullptr,
            has_next ? fc1_b + (k + 1) * 128 : nullptr,
            h1out, (k == 3) ? (float*)d_out : nullptr, N, has_next);
    }
}